// Round 8
// baseline (793.504 us; speedup 1.0000x reference)
//
#include <hip/hip_runtime.h>
#include <math.h>

#define RFL(x) __builtin_amdgcn_readfirstlane(x)
#define RL(x, l) __int_as_float(__builtin_amdgcn_readlane(__float_as_int(x), (l)))

// ---------------- degree histogram (int) ----------------

__global__ __launch_bounds__(256) void k_zero(int* p, int n) {
  int t = blockIdx.x * 256 + threadIdx.x;
  if (t < n) p[t] = 0;
}

__global__ __launch_bounds__(256) void k_count(const int* __restrict__ dst, int* cnt, int E) {
  int stride = gridDim.x * blockDim.x;
  for (int e = blockIdx.x * blockDim.x + threadIdx.x; e < E; e += stride)
    atomicAdd(&cnt[dst[e]], 1);
}

// ---------------- exclusive scan: cnt -> row_start ----------------

__global__ __launch_bounds__(256) void k_scan1(const int* __restrict__ cnt, int* __restrict__ row,
                                               int* __restrict__ partial, int N) {
  __shared__ int sm[256];
  int t = threadIdx.x, g = blockIdx.x * 256 + t;
  int v = (g < N) ? cnt[g] : 0;
  sm[t] = v;
  __syncthreads();
#pragma unroll
  for (int off = 1; off < 256; off <<= 1) {
    int x = 0;
    if (t >= off) x = sm[t - off];
    __syncthreads();
    if (t >= off) sm[t] += x;
    __syncthreads();
  }
  if (g < N) row[g] = sm[t] - v;  // exclusive within block
  if (t == 255) partial[blockIdx.x] = sm[255];
}

__global__ __launch_bounds__(256) void k_scan2(int* __restrict__ partial, int P) {
  __shared__ int sm[256];
  int t = threadIdx.x;
  int carry = 0;
  for (int base = 0; base < P; base += 256) {
    int idx = base + t;
    int v = (idx < P) ? partial[idx] : 0;
    sm[t] = v;
    __syncthreads();
#pragma unroll
    for (int off = 1; off < 256; off <<= 1) {
      int x = 0;
      if (t >= off) x = sm[t - off];
      __syncthreads();
      if (t >= off) sm[t] += x;
      __syncthreads();
    }
    if (idx < P) partial[idx] = carry + sm[t] - v;  // exclusive
    int tot = sm[255];
    __syncthreads();
    carry += tot;
  }
}

// scan3 + dinv fused (cnt is final here; dinv first consumed after this point)
__global__ __launch_bounds__(256) void k_scan3(int* __restrict__ row, const int* __restrict__ partial,
                                               int* __restrict__ cursor, const int* __restrict__ cnt,
                                               float* __restrict__ dinv, int N) {
  int g = blockIdx.x * 256 + threadIdx.x;
  if (g < N) {
    int v = row[g] + partial[blockIdx.x];
    row[g] = v;
    cursor[g] = v;
    dinv[g] = rsqrtf((float)cnt[g] + 1.0f);  // +1 self-loop
  }
}

// ---------------- edge placement: dst-sorted src ----------------

__global__ __launch_bounds__(256) void k_edge_fill(const int* __restrict__ src, const int* __restrict__ dst,
                                                   int* __restrict__ cursor, int* __restrict__ esrc, int E) {
  int stride = gridDim.x * blockDim.x;
  for (int e = blockIdx.x * blockDim.x + threadIdx.x; e < E; e += stride) {
    int s = src[e], d = dst[e];
    int pos = atomicAdd(&cursor[d], 1);
    esrc[pos] = s;
  }
}

// ---------------- W_c = W_out @ W1, b_c = b_out @ W1 ----------------

__global__ __launch_bounds__(256) void k_wc(const float* __restrict__ Wout, const float* __restrict__ bout,
                                            const float* __restrict__ W1, float* __restrict__ Wc,
                                            float* __restrict__ bc) {
  int t = blockIdx.x * 256 + threadIdx.x;
  if (t >= 65 * 128) return;
  int h = t >> 7, o = t & 127;
  const float* row = (h < 64) ? (Wout + h * 128) : bout;
  float a = 0.f;
  for (int d = 0; d < 128; ++d) a += row[d] * W1[d * 128 + o];
  if (h < 64) Wc[h * 128 + o] = a;
  else bc[o] = a;
}

// ---------------- attention pooling (X-stationary, WE in LDS) ----------------
// Block = 512 threads = 8 waves; each wave owns 60 consecutive set-rows = 3 nodes
// (lane = row; lanes 60-63 idle). WE (32KB) staged in LDS once per block; inner
// loop reads it with uniform-address ds_read_b128 (broadcast, conflict-free) so
// the SGPR file no longer throttles prefetch. Lane accumulates z[64] in VGPRs.
// Epilogue: group-of-20 softmax + pooled sum via predicated __shfl_down chains
// (no extra LDS, no block barriers after staging).

__global__ __launch_bounds__(512, 4) void k_pool(const float* __restrict__ X, const int* __restrict__ mask,
                                                 const float* __restrict__ WE, const float* __restrict__ bE,
                                                 const float* __restrict__ WA, const float* __restrict__ bA,
                                                 float* __restrict__ pz, int N) {
  __shared__ float lws[8192];  // WE: [d=128][h=64]
  const int lane = threadIdx.x & 63;
  const int wid = threadIdx.x >> 6;  // 0..7

  for (int i = threadIdx.x; i < 2048; i += 512)
    ((float4*)lws)[i] = ((const float4*)WE)[i];
  __syncthreads();

  const long long totRows = (long long)N * 20;
  long long row = (long long)blockIdx.x * 480 + wid * 60 + lane;
  const float* __restrict__ xr = X + (row < totRows ? row : (totRows - 1)) * 128;

  float acc[64];
#pragma unroll
  for (int h = 0; h < 64; ++h) acc[h] = 0.f;

  float x[8], xn[8];
  *(float4*)&x[0] = *(const float4*)(xr + 0);
  *(float4*)&x[4] = *(const float4*)(xr + 4);

#pragma unroll 2
  for (int c = 0; c < 16; ++c) {
    const int cn = (c + 1) & 15;  // wrap: chunk-15 prefetches chunk-0 again (harmless)
    *(float4*)&xn[0] = *(const float4*)(xr + cn * 8 + 0);
    *(float4*)&xn[4] = *(const float4*)(xr + cn * 8 + 4);
    const float* __restrict__ wp = lws + c * 512;
#pragma unroll
    for (int d = 0; d < 8; ++d) {
#pragma unroll
      for (int hq = 0; hq < 16; ++hq) {
        const float4 we = *(const float4*)(wp + d * 64 + hq * 4);  // uniform ds_read_b128
        acc[hq * 4 + 0] += we.x * x[d];
        acc[hq * 4 + 1] += we.y * x[d];
        acc[hq * 4 + 2] += we.z * x[d];
        acc[hq * 4 + 3] += we.w * x[d];
      }
    }
#pragma unroll
    for (int d = 0; d < 8; ++d) x[d] = xn[d];
  }

  // z = relu(acc + bE); score = z . WA + bA
  float sc = bA[0];
#pragma unroll
  for (int h = 0; h < 64; ++h) {
    float z = fmaxf(acc[h] + bE[h], 0.f);
    acc[h] = z;
    sc = fmaf(z, WA[h], sc);
  }

  const int ln = (lane < 60) ? (lane / 20) : 0;  // node-in-wave 0..2
  const int s_in = lane - ln * 20;               // 0..19 (60..63 for idle lanes)
  const int node = blockIdx.x * 24 + wid * 3 + ln;
  const bool act = (lane < 60) && (node < N);
  const int mk = act ? mask[node * 20 + s_in] : 0;
  const float NEG = -3.0e38f;
  if (!act || mk == 0) sc = NEG;

  // group-of-20 max via predicated shfl_down, then broadcast from group leader
  float mx = sc;
#pragma unroll
  for (int off = 1; off < 32; off <<= 1) {
    float o = __shfl_down(mx, off, 64);
    if (s_in + off < 20) mx = fmaxf(mx, o);
  }
  mx = __shfl(mx, ln * 20, 64);
  const float p = (sc == NEG) ? 0.f : __expf(sc - mx);  // masked -> exactly 0, no NaN
  float den = p;
#pragma unroll
  for (int off = 1; off < 32; off <<= 1) {
    float o = __shfl_down(den, off, 64);
    if (s_in + off < 20) den += o;
  }
  den = __shfl(den, ln * 20, 64);
  const float wgt = p / fmaxf(den, 1e-37f);  // dead groups: 0/eps = 0, no NaN
#pragma unroll
  for (int h = 0; h < 64; ++h) acc[h] *= wgt;

  // pooled[node][h] = sum over the node's 20 lanes; packed float4 stores from leader
  float4 ob;
#pragma unroll
  for (int h = 0; h < 64; ++h) {
    float v = acc[h];
#pragma unroll
    for (int off = 1; off < 32; off <<= 1) {
      float o = __shfl_down(v, off, 64);
      if (s_in + off < 20) v += o;
    }
    if ((h & 3) == 0) ob.x = v;
    else if ((h & 3) == 1) ob.y = v;
    else if ((h & 3) == 2) ob.z = v;
    else {
      ob.w = v;
      if (s_in == 0 && act) ((float4*)pz)[(size_t)node * 16 + (h >> 2)] = ob;
    }
  }
}

// ---------------- h1p = (pz @ Wc + bc) * dinv[r] ----------------

__global__ __launch_bounds__(256, 2) void k_gemm1(const float* __restrict__ pz, const float* __restrict__ Wc,
                                                  const float* __restrict__ bc, const float* __restrict__ dinv,
                                                  float* __restrict__ h1p, int N) {
  const int lane = threadIdx.x & 63;
  float w0[64], w1[64];
#pragma unroll
  for (int d = 0; d < 64; ++d) {
    w0[d] = Wc[d * 128 + lane];
    w1[d] = Wc[d * 128 + 64 + lane];
  }
  const float b0 = bc[lane], b1v = bc[64 + lane];
  const int nw = (gridDim.x * blockDim.x) >> 6;
  const int w_id = (blockIdx.x * blockDim.x + threadIdx.x) >> 6;
  for (int r = w_id; r < N; r += nw) {
    const float xv = pz[(size_t)r * 64 + lane];
    const int xi = __float_as_int(xv);
    float p0 = 0.f, p1 = 0.f, p2 = 0.f, p3 = 0.f;
#pragma unroll
    for (int d0 = 0; d0 < 64; d0 += 2) {
      float a0 = RL((float&)xi, d0);
      float a1 = RL((float&)xi, d0 + 1);
      p0 += a0 * w0[d0];
      p1 += a0 * w1[d0];
      p2 += a1 * w0[d0 + 1];
      p3 += a1 * w1[d0 + 1];
    }
    float di = dinv[r];
    size_t o = (size_t)r * 128 + lane;
    h1p[o] = (b0 + p0 + p2) * di;
    h1p[o + 64] = (b1v + p1 + p3) * di;
  }
}

// ---------------- gather layer 1: x1[d] = dinv[d]*(sum_in h1p[s] + h1p[d]*dinv[d]) ----------------
// one wave per dst node; two 32-lane halves take alternate edges (4-deep each
// -> 8 float4 gathers in flight/wave); combine via shfl_xor(32).

__global__ __launch_bounds__(256) void k_gather1(const int* __restrict__ row, const int* __restrict__ cnt,
                                                 const int* __restrict__ esrc, const float* __restrict__ h1p,
                                                 const float* __restrict__ dinv, float* __restrict__ x1, int N) {
  const int lane = threadIdx.x & 63;
  const int node = RFL(blockIdx.x * 4 + (threadIdx.x >> 6));
  if (node >= N) return;
  const int half = lane >> 5, f4 = lane & 31;
  const int rs = RFL(row[node]);
  const int ne = RFL(cnt[node]);
  const float di = dinv[node];
  const float4* __restrict__ hv = (const float4*)h1p;
  float a0 = 0.f, a1 = 0.f, a2 = 0.f, a3 = 0.f;
  int j = half;
  for (; j + 7 <= ne; j += 8) {  // edges j, j+2, j+4, j+6 for this half
    int s0 = esrc[rs + j], s1 = esrc[rs + j + 2], s2 = esrc[rs + j + 4], s3 = esrc[rs + j + 6];
    float4 v0 = hv[(size_t)s0 * 32 + f4];
    float4 v1 = hv[(size_t)s1 * 32 + f4];
    float4 v2 = hv[(size_t)s2 * 32 + f4];
    float4 v3 = hv[(size_t)s3 * 32 + f4];
    a0 += v0.x + v1.x + v2.x + v3.x;
    a1 += v0.y + v1.y + v2.y + v3.y;
    a2 += v0.z + v1.z + v2.z + v3.z;
    a3 += v0.w + v1.w + v2.w + v3.w;
  }
  for (; j < ne; j += 2) {
    int s = esrc[rs + j];
    float4 v = hv[(size_t)s * 32 + f4];
    a0 += v.x; a1 += v.y; a2 += v.z; a3 += v.w;
  }
  a0 += __shfl_xor(a0, 32, 64);
  a1 += __shfl_xor(a1, 32, 64);
  a2 += __shfl_xor(a2, 32, 64);
  a3 += __shfl_xor(a3, 32, 64);
  if (half == 0) {
    float4 sv = hv[(size_t)node * 32 + f4];
    float4 o;
    o.x = (a0 + sv.x * di) * di;
    o.y = (a1 + sv.y * di) * di;
    o.z = (a2 + sv.z * di) * di;
    o.w = (a3 + sv.w * di) * di;
    ((float4*)x1)[(size_t)node * 32 + f4] = o;
  }
}

// ---------------- h2p = (relu(x1 + b1) @ W2) * dinv[r] ----------------

__global__ __launch_bounds__(256, 2) void k_gemm2(const float* __restrict__ x1, const float* __restrict__ b1,
                                                  const float* __restrict__ W2, const float* __restrict__ dinv,
                                                  float* __restrict__ h2p, int N) {
  const int lane = threadIdx.x & 63;
  const int col = lane & 31;
  float w[128];
#pragma unroll
  for (int d = 0; d < 128; ++d) w[d] = W2[d * 32 + col];
  const float bb0 = b1[lane], bb1 = b1[64 + lane];
  const int nw = (gridDim.x * blockDim.x) >> 6;
  const int w_id = (blockIdx.x * blockDim.x + threadIdx.x) >> 6;
  for (int r = w_id; r < N; r += nw) {
    float rx0 = fmaxf(x1[(size_t)r * 128 + lane] + bb0, 0.f);
    float rx1 = fmaxf(x1[(size_t)r * 128 + 64 + lane] + bb1, 0.f);
    const int xi0 = __float_as_int(rx0), xi1 = __float_as_int(rx1);
    float p0 = 0.f, p1 = 0.f, p2 = 0.f, p3 = 0.f;
#pragma unroll
    for (int d0 = 0; d0 < 64; d0 += 2) {
      float a0 = RL((float&)xi0, d0);
      float a1 = RL((float&)xi0, d0 + 1);
      float c0 = RL((float&)xi1, d0);
      float c1 = RL((float&)xi1, d0 + 1);
      p0 += a0 * w[d0];
      p1 += a1 * w[d0 + 1];
      p2 += c0 * w[64 + d0];
      p3 += c1 * w[64 + d0 + 1];
    }
    if (lane < 32) {
      float di = dinv[r];
      h2p[(size_t)r * 32 + col] = ((p0 + p1) + (p2 + p3)) * di;
    }
  }
}

// ---------------- gather layer 2: 8 groups of 8 lanes (float4), 2-deep ----------------
// 16 edges in flight per wave; combine via shfl_xor 8/16/32.

__global__ __launch_bounds__(256) void k_gather2(const int* __restrict__ row, const int* __restrict__ cnt,
                                                 const int* __restrict__ esrc, const float* __restrict__ h2p,
                                                 const float* __restrict__ dinv, float* __restrict__ x2, int N) {
  const int lane = threadIdx.x & 63;
  const int node = RFL(blockIdx.x * 4 + (threadIdx.x >> 6));
  if (node >= N) return;
  const int q = lane >> 3, f4 = lane & 7;  // group 0..7, float4 slot 0..7 (8x4=32 floats)
  const int rs = RFL(row[node]);
  const int ne = RFL(cnt[node]);
  const float di = dinv[node];
  const float4* __restrict__ hv = (const float4*)h2p;
  float a0 = 0.f, a1 = 0.f, a2 = 0.f, a3 = 0.f;
  int j = q;
  for (; j + 9 <= ne; j += 16) {  // edges j and j+8 for this group
    int s0 = esrc[rs + j], s1 = esrc[rs + j + 8];
    float4 v0 = hv[(size_t)s0 * 8 + f4];
    float4 v1 = hv[(size_t)s1 * 8 + f4];
    a0 += v0.x + v1.x;
    a1 += v0.y + v1.y;
    a2 += v0.z + v1.z;
    a3 += v0.w + v1.w;
  }
  for (; j < ne; j += 8) {
    int s = esrc[rs + j];
    float4 v = hv[(size_t)s * 8 + f4];
    a0 += v.x; a1 += v.y; a2 += v.z; a3 += v.w;
  }
#pragma unroll
  for (int off = 8; off <= 32; off <<= 1) {
    a0 += __shfl_xor(a0, off, 64);
    a1 += __shfl_xor(a1, off, 64);
    a2 += __shfl_xor(a2, off, 64);
    a3 += __shfl_xor(a3, off, 64);
  }
  if (q == 0) {
    float4 sv = hv[(size_t)node * 8 + f4];
    float4 o;
    o.x = (a0 + sv.x * di) * di;
    o.y = (a1 + sv.y * di) * di;
    o.z = (a2 + sv.z * di) * di;
    o.w = (a3 + sv.w * di) * di;
    ((float4*)x2)[(size_t)node * 8 + f4] = o;
  }
}

// ---------------- query MLP ----------------

__global__ __launch_bounds__(256) void k_mlp(const int* __restrict__ qidx, const float* __restrict__ x2,
                                             const float* __restrict__ b2, const float* __restrict__ Wm1,
                                             const float* __restrict__ bm1, const float* __restrict__ Wm2,
                                             const float* __restrict__ bm2, float* __restrict__ out, int B) {
  int t = blockIdx.x * 256 + threadIdx.x;
  if (t >= B) return;
  int n = qidx[t];
  float qv[32];
#pragma unroll
  for (int k = 0; k < 32; ++k) qv[k] = fmaxf(x2[(size_t)n * 32 + k] + b2[k], 0.f);
  float acc = bm2[0];
  for (int j = 0; j < 64; ++j) {
    float h = bm1[j];
#pragma unroll
    for (int k = 0; k < 32; ++k) h += qv[k] * Wm1[k * 64 + j];
    acc += fmaxf(h, 0.f) * Wm2[j];
  }
  out[t] = acc;
}

// ---------------- launcher ----------------

extern "C" void kernel_launch(void* const* d_in, const int* in_sizes, int n_in,
                              void* d_out, int out_size, void* d_ws, size_t ws_size,
                              hipStream_t stream) {
  const float* X    = (const float*)d_in[0];
  const int*   mask = (const int*)d_in[1];
  const int*   ei   = (const int*)d_in[2];
  const int*   qidx = (const int*)d_in[3];
  const float* WE   = (const float*)d_in[4];
  const float* bE   = (const float*)d_in[5];
  const float* WA   = (const float*)d_in[6];
  const float* bA   = (const float*)d_in[7];
  const float* Wout = (const float*)d_in[8];
  const float* bout = (const float*)d_in[9];
  const float* W1   = (const float*)d_in[10];
  const float* b1   = (const float*)d_in[11];
  const float* W2   = (const float*)d_in[12];
  const float* b2   = (const float*)d_in[13];
  const float* Wm1  = (const float*)d_in[14];
  const float* bm1  = (const float*)d_in[15];
  const float* Wm2  = (const float*)d_in[16];
  const float* bm2  = (const float*)d_in[17];

  const int N = in_sizes[1] / 20;
  const int E = in_sizes[2] / 2;
  const int B = in_sizes[3];
  const int* src  = ei;
  const int* dstp = ei + E;

  const size_t Na = ((size_t)N + 63) & ~(size_t)63;
  const size_t Ea = ((size_t)E + 63) & ~(size_t)63;
  const int P = (N + 255) / 256;
  const size_t Pa = ((size_t)P + 63) & ~(size_t)63;

  float* ws      = (float*)d_ws;
  float* dinv    = ws;                       // N
  int*   cnt     = (int*)(dinv + Na);        // N
  int*   rowp    = cnt + Na;                 // N
  int*   cursor  = rowp + Na;                // N
  int*   partial = cursor + Na;              // P
  int*   esrc    = partial + Pa;             // E
  float* Wc      = (float*)(esrc + Ea);      // 8192
  float* bc      = Wc + 8192;                // 128
  float* pz      = bc + 128;                 // N*64
  float* h1p     = pz + (size_t)N * 64;      // N*128
  float* x1      = h1p + (size_t)N * 128;    // N*128
  float* h2p     = pz;                       // reuse pz (dead after gemm1): N*32
  float* x2      = pz + (size_t)N * 32;      // N*32

  const int nb = (N + 255) / 256;
  const int nw4 = (N + 3) / 4;
  const int nb24 = (N + 23) / 24;

  k_zero<<<nb, 256, 0, stream>>>(cnt, N);
  k_count<<<1024, 256, 0, stream>>>(dstp, cnt, E);
  k_scan1<<<P, 256, 0, stream>>>(cnt, rowp, partial, N);
  k_scan2<<<1, 256, 0, stream>>>(partial, P);
  k_scan3<<<P, 256, 0, stream>>>(rowp, partial, cursor, cnt, dinv, N);
  k_edge_fill<<<1024, 256, 0, stream>>>(src, dstp, cursor, esrc, E);
  k_wc<<<33, 256, 0, stream>>>(Wout, bout, W1, Wc, bc);
  k_pool<<<nb24, 512, 0, stream>>>(X, mask, WE, bE, WA, bA, pz, N);
  k_gemm1<<<1024, 256, 0, stream>>>(pz, Wc, bc, dinv, h1p, N);
  k_gather1<<<nw4, 256, 0, stream>>>(rowp, cnt, esrc, h1p, dinv, x1, N);
  k_gemm2<<<1024, 256, 0, stream>>>(x1, b1, W2, dinv, h2p, N);
  k_gather2<<<nw4, 256, 0, stream>>>(rowp, cnt, esrc, h2p, dinv, x2, N);
  k_mlp<<<(B + 255) / 256, 256, 0, stream>>>(qidx, x2, b2, Wm1, bm1, Wm2, bm2, (float*)d_out, B);
}

// Round 9
// 658.591 us; speedup vs baseline: 1.2049x; 1.2049x over previous
//
#include <hip/hip_runtime.h>
#include <math.h>

#define RFL(x) __builtin_amdgcn_readfirstlane(x)
#define RL(x, l) __int_as_float(__builtin_amdgcn_readlane(__float_as_int(x), (l)))

typedef __attribute__((ext_vector_type(8))) short bf16x8;
typedef __attribute__((ext_vector_type(4))) float f32x4;

__device__ inline unsigned short bf16_rne(float f) {
  unsigned u = __float_as_uint(f);
  u += 0x7FFFu + ((u >> 16) & 1u);
  return (unsigned short)(u >> 16);
}

// ---------------- degree histogram (int) ----------------

__global__ __launch_bounds__(256) void k_zero(int* p, int n) {
  int t = blockIdx.x * 256 + threadIdx.x;
  if (t < n) p[t] = 0;
}

__global__ __launch_bounds__(256) void k_count(const int* __restrict__ dst, int* cnt, int E) {
  int stride = gridDim.x * blockDim.x;
  for (int e = blockIdx.x * blockDim.x + threadIdx.x; e < E; e += stride)
    atomicAdd(&cnt[dst[e]], 1);
}

// ---------------- exclusive scan: cnt -> row_start ----------------

__global__ __launch_bounds__(256) void k_scan1(const int* __restrict__ cnt, int* __restrict__ row,
                                               int* __restrict__ partial, int N) {
  __shared__ int sm[256];
  int t = threadIdx.x, g = blockIdx.x * 256 + t;
  int v = (g < N) ? cnt[g] : 0;
  sm[t] = v;
  __syncthreads();
#pragma unroll
  for (int off = 1; off < 256; off <<= 1) {
    int x = 0;
    if (t >= off) x = sm[t - off];
    __syncthreads();
    if (t >= off) sm[t] += x;
    __syncthreads();
  }
  if (g < N) row[g] = sm[t] - v;  // exclusive within block
  if (t == 255) partial[blockIdx.x] = sm[255];
}

__global__ __launch_bounds__(256) void k_scan2(int* __restrict__ partial, int P) {
  __shared__ int sm[256];
  int t = threadIdx.x;
  int carry = 0;
  for (int base = 0; base < P; base += 256) {
    int idx = base + t;
    int v = (idx < P) ? partial[idx] : 0;
    sm[t] = v;
    __syncthreads();
#pragma unroll
    for (int off = 1; off < 256; off <<= 1) {
      int x = 0;
      if (t >= off) x = sm[t - off];
      __syncthreads();
      if (t >= off) sm[t] += x;
      __syncthreads();
    }
    if (idx < P) partial[idx] = carry + sm[t] - v;  // exclusive
    int tot = sm[255];
    __syncthreads();
    carry += tot;
  }
}

// scan3 + dinv fused
__global__ __launch_bounds__(256) void k_scan3(int* __restrict__ row, const int* __restrict__ partial,
                                               int* __restrict__ cursor, const int* __restrict__ cnt,
                                               float* __restrict__ dinv, int N) {
  int g = blockIdx.x * 256 + threadIdx.x;
  if (g < N) {
    int v = row[g] + partial[blockIdx.x];
    row[g] = v;
    cursor[g] = v;
    dinv[g] = rsqrtf((float)cnt[g] + 1.0f);  // +1 self-loop
  }
}

// ---------------- edge placement: dst-sorted src ----------------

__global__ __launch_bounds__(256) void k_edge_fill(const int* __restrict__ src, const int* __restrict__ dst,
                                                   int* __restrict__ cursor, int* __restrict__ esrc, int E) {
  int stride = gridDim.x * blockDim.x;
  for (int e = blockIdx.x * blockDim.x + threadIdx.x; e < E; e += stride) {
    int s = src[e], d = dst[e];
    int pos = atomicAdd(&cursor[d], 1);
    esrc[pos] = s;
  }
}

// ---------------- W_c = W_out @ W1, b_c = b_out @ W1 ----------------

__global__ __launch_bounds__(256) void k_wc(const float* __restrict__ Wout, const float* __restrict__ bout,
                                            const float* __restrict__ W1, float* __restrict__ Wc,
                                            float* __restrict__ bc) {
  int t = blockIdx.x * 256 + threadIdx.x;
  if (t >= 65 * 128) return;
  int h = t >> 7, o = t & 127;
  const float* row = (h < 64) ? (Wout + h * 128) : bout;
  float a = 0.f;
  for (int d = 0; d < 128; ++d) a += row[d] * W1[d * 128 + o];
  if (h < 64) Wc[h * 128 + o] = a;
  else bc[o] = a;
}

// ---------------- attention pooling via MFMA (split-bf16) ----------------
// Block = 256 thr / 4 waves, owns 80 rows = 4 nodes (LCM(16,20)).
// X tile staged to LDS as bf16 hi/lo ([80][136] pad -> 2-way banks, free).
// Wave w owns output col-tile [16w,16w+16): WE B-frags (hi/lo x 4 ksteps) in regs.
// Z = Xh*Wh + Xh*Wl + Xl*Wh via mfma_f32_16x16x32_bf16, f32 accumulate
// (~fp32 precision). C layout: col=lane&15, row=(lane>>4)*4+reg (verified).
// Epilogue: score = relu(Z+bE).WA via 16-lane shfl reduce -> softmax over each
// node's 20 rows in LDS -> weighted z -> pooled sum, coalesced pz store.

__global__ __launch_bounds__(256, 2) void k_pool(const float* __restrict__ X, const int* __restrict__ mask,
                                                 const float* __restrict__ WE, const float* __restrict__ bE,
                                                 const float* __restrict__ WA, const float* __restrict__ bA,
                                                 float* __restrict__ pz, int N) {
  __shared__ __align__(16) unsigned short Xh[80][136];
  __shared__ __align__(16) unsigned short Xl[80][136];
  __shared__ float scorep[80][4];
  __shared__ float sco[80];
  __shared__ float parr[80];
  __shared__ float wgtA[80];
  __shared__ float zt[80][68];

  const int t = threadIdx.x;
  const int lane = t & 63;
  const int wv = t >> 6;     // wave 0..3 = col tile
  const int cb = wv * 16;
  const int l16 = lane & 15;
  const int lg = lane >> 4;  // 0..3

  const long long totRows = (long long)N * 20;
  const long long rowBase = (long long)blockIdx.x * 80;

  // ---- stage X tile -> LDS as split bf16 ----
#pragma unroll
  for (int q = 0; q < 10; ++q) {
    int idx = q * 256 + t;  // float4 index in 80x128 tile
    int r = idx >> 5, kq = idx & 31;
    long long rr = rowBase + r;
    if (rr >= totRows) rr = totRows - 1;
    const float4 v = *(const float4*)(X + rr * 128 + kq * 4);
    unsigned short h0 = bf16_rne(v.x), h1 = bf16_rne(v.y), h2 = bf16_rne(v.z), h3 = bf16_rne(v.w);
    float f0 = __uint_as_float((unsigned)h0 << 16);
    float f1 = __uint_as_float((unsigned)h1 << 16);
    float f2 = __uint_as_float((unsigned)h2 << 16);
    float f3 = __uint_as_float((unsigned)h3 << 16);
    ushort4 hv = make_ushort4(h0, h1, h2, h3);
    ushort4 lv = make_ushort4(bf16_rne(v.x - f0), bf16_rne(v.y - f1),
                              bf16_rne(v.z - f2), bf16_rne(v.w - f3));
    *(ushort4*)&Xh[r][kq * 4] = hv;
    *(ushort4*)&Xl[r][kq * 4] = lv;
  }

  // ---- B fragments (WE col-tile) in registers, hi/lo ----
  bf16x8 bh[4], bl[4];
#pragma unroll
  for (int kk = 0; kk < 4; ++kk) {
    union { bf16x8 v; unsigned short s[8]; } uh, ul;
#pragma unroll
    for (int i = 0; i < 8; ++i) {
      int k = kk * 32 + lg * 8 + i;
      float w = WE[k * 64 + cb + l16];
      unsigned short h = bf16_rne(w);
      uh.s[i] = h;
      ul.s[i] = bf16_rne(w - __uint_as_float((unsigned)h << 16));
    }
    bh[kk] = uh.v;
    bl[kk] = ul.v;
  }
  __syncthreads();

  // ---- MFMA: Z[80][16 cols of this wave] ----
  f32x4 acc[5];
#pragma unroll
  for (int rt = 0; rt < 5; ++rt) acc[rt] = (f32x4){0.f, 0.f, 0.f, 0.f};
#pragma unroll
  for (int rt = 0; rt < 5; ++rt) {
    const int rl = rt * 16 + l16;
#pragma unroll
    for (int kk = 0; kk < 4; ++kk) {
      const int ko = kk * 32 + lg * 8;
      bf16x8 ah = *(const bf16x8*)&Xh[rl][ko];
      bf16x8 al = *(const bf16x8*)&Xl[rl][ko];
      acc[rt] = __builtin_amdgcn_mfma_f32_16x16x32_bf16(ah, bh[kk], acc[rt], 0, 0, 0);
      acc[rt] = __builtin_amdgcn_mfma_f32_16x16x32_bf16(ah, bl[kk], acc[rt], 0, 0, 0);
      acc[rt] = __builtin_amdgcn_mfma_f32_16x16x32_bf16(al, bh[kk], acc[rt], 0, 0, 0);
    }
  }

  // ---- relu + per-row score partials (this wave's 16 cols) ----
  const float bEv = bE[cb + l16];
  const float WAv = WA[cb + l16];
#pragma unroll
  for (int rt = 0; rt < 5; ++rt) {
#pragma unroll
    for (int j = 0; j < 4; ++j) {
      float z = fmaxf(acc[rt][j] + bEv, 0.f);
      acc[rt][j] = z;
      float v = z * WAv;
      v += __shfl_xor(v, 1, 64);
      v += __shfl_xor(v, 2, 64);
      v += __shfl_xor(v, 4, 64);
      v += __shfl_xor(v, 8, 64);
      if (l16 == 0) scorep[rt * 16 + lg * 4 + j][wv] = v;
    }
  }
  __syncthreads();

  // ---- softmax over each node's 20 rows ----
  const float NEG = -3.0e38f;
  if (t < 80) {
    float4 sp = *(const float4*)scorep[t];
    float sc = sp.x + sp.y + sp.z + sp.w + bA[0];
    int node_l = t / 20, s_in = t - node_l * 20;
    long long node = (long long)blockIdx.x * 4 + node_l;
    int mk = (node < N) ? mask[node * 20 + s_in] : 0;
    if (mk == 0) sc = NEG;
    sco[t] = sc;
  }
  __syncthreads();
  if (t < 80) {
    int base = (t / 20) * 20;
    float mx = NEG;
#pragma unroll
    for (int i = 0; i < 20; ++i) mx = fmaxf(mx, sco[base + i]);
    float sc = sco[t];
    parr[t] = (sc <= -1.0e38f) ? 0.f : __expf(sc - mx);
  }
  __syncthreads();
  if (t < 80) {
    int base = (t / 20) * 20;
    float den = 0.f;
#pragma unroll
    for (int i = 0; i < 20; ++i) den += parr[base + i];
    wgtA[t] = parr[t] / fmaxf(den, 1e-37f);
  }
  __syncthreads();

  // ---- weighted z -> LDS ----
#pragma unroll
  for (int rt = 0; rt < 5; ++rt) {
#pragma unroll
    for (int j = 0; j < 4; ++j) {
      int row = rt * 16 + lg * 4 + j;
      zt[row][cb + l16] = acc[rt][j] * wgtA[row];
    }
  }
  __syncthreads();

  // ---- pooled[n][col] = sum over 20 rows; coalesced store ----
  {
    int n = t >> 6, col = t & 63;
    float s = 0.f;
#pragma unroll
    for (int i = 0; i < 20; ++i) s += zt[n * 20 + i][col];
    long long node = (long long)blockIdx.x * 4 + n;
    if (node < N) pz[node * 64 + col] = s;
  }
}

// ---------------- h1p = (pz @ Wc + bc) * dinv[r] ----------------

__global__ __launch_bounds__(256, 2) void k_gemm1(const float* __restrict__ pz, const float* __restrict__ Wc,
                                                  const float* __restrict__ bc, const float* __restrict__ dinv,
                                                  float* __restrict__ h1p, int N) {
  const int lane = threadIdx.x & 63;
  float w0[64], w1[64];
#pragma unroll
  for (int d = 0; d < 64; ++d) {
    w0[d] = Wc[d * 128 + lane];
    w1[d] = Wc[d * 128 + 64 + lane];
  }
  const float b0 = bc[lane], b1v = bc[64 + lane];
  const int nw = (gridDim.x * blockDim.x) >> 6;
  const int w_id = (blockIdx.x * blockDim.x + threadIdx.x) >> 6;
  for (int r = w_id; r < N; r += nw) {
    const float xv = pz[(size_t)r * 64 + lane];
    const int xi = __float_as_int(xv);
    float p0 = 0.f, p1 = 0.f, p2 = 0.f, p3 = 0.f;
#pragma unroll
    for (int d0 = 0; d0 < 64; d0 += 2) {
      float a0 = RL((float&)xi, d0);
      float a1 = RL((float&)xi, d0 + 1);
      p0 += a0 * w0[d0];
      p1 += a0 * w1[d0];
      p2 += a1 * w0[d0 + 1];
      p3 += a1 * w1[d0 + 1];
    }
    float di = dinv[r];
    size_t o = (size_t)r * 128 + lane;
    h1p[o] = (b0 + p0 + p2) * di;
    h1p[o + 64] = (b1v + p1 + p3) * di;
  }
}

// ---------------- gather layer 1 ----------------

__global__ __launch_bounds__(256) void k_gather1(const int* __restrict__ row, const int* __restrict__ cnt,
                                                 const int* __restrict__ esrc, const float* __restrict__ h1p,
                                                 const float* __restrict__ dinv, float* __restrict__ x1, int N) {
  const int lane = threadIdx.x & 63;
  const int node = RFL(blockIdx.x * 4 + (threadIdx.x >> 6));
  if (node >= N) return;
  const int half = lane >> 5, f4 = lane & 31;
  const int rs = RFL(row[node]);
  const int ne = RFL(cnt[node]);
  const float di = dinv[node];
  const float4* __restrict__ hv = (const float4*)h1p;
  float a0 = 0.f, a1 = 0.f, a2 = 0.f, a3 = 0.f;
  int j = half;
  for (; j + 7 <= ne; j += 8) {
    int s0 = esrc[rs + j], s1 = esrc[rs + j + 2], s2 = esrc[rs + j + 4], s3 = esrc[rs + j + 6];
    float4 v0 = hv[(size_t)s0 * 32 + f4];
    float4 v1 = hv[(size_t)s1 * 32 + f4];
    float4 v2 = hv[(size_t)s2 * 32 + f4];
    float4 v3 = hv[(size_t)s3 * 32 + f4];
    a0 += v0.x + v1.x + v2.x + v3.x;
    a1 += v0.y + v1.y + v2.y + v3.y;
    a2 += v0.z + v1.z + v2.z + v3.z;
    a3 += v0.w + v1.w + v2.w + v3.w;
  }
  for (; j < ne; j += 2) {
    int s = esrc[rs + j];
    float4 v = hv[(size_t)s * 32 + f4];
    a0 += v.x; a1 += v.y; a2 += v.z; a3 += v.w;
  }
  a0 += __shfl_xor(a0, 32, 64);
  a1 += __shfl_xor(a1, 32, 64);
  a2 += __shfl_xor(a2, 32, 64);
  a3 += __shfl_xor(a3, 32, 64);
  if (half == 0) {
    float4 sv = hv[(size_t)node * 32 + f4];
    float4 o;
    o.x = (a0 + sv.x * di) * di;
    o.y = (a1 + sv.y * di) * di;
    o.z = (a2 + sv.z * di) * di;
    o.w = (a3 + sv.w * di) * di;
    ((float4*)x1)[(size_t)node * 32 + f4] = o;
  }
}

// ---------------- h2p = (relu(x1 + b1) @ W2) * dinv[r] ----------------

__global__ __launch_bounds__(256, 2) void k_gemm2(const float* __restrict__ x1, const float* __restrict__ b1,
                                                  const float* __restrict__ W2, const float* __restrict__ dinv,
                                                  float* __restrict__ h2p, int N) {
  const int lane = threadIdx.x & 63;
  const int col = lane & 31;
  float w[128];
#pragma unroll
  for (int d = 0; d < 128; ++d) w[d] = W2[d * 32 + col];
  const float bb0 = b1[lane], bb1 = b1[64 + lane];
  const int nw = (gridDim.x * blockDim.x) >> 6;
  const int w_id = (blockIdx.x * blockDim.x + threadIdx.x) >> 6;
  for (int r = w_id; r < N; r += nw) {
    float rx0 = fmaxf(x1[(size_t)r * 128 + lane] + bb0, 0.f);
    float rx1 = fmaxf(x1[(size_t)r * 128 + 64 + lane] + bb1, 0.f);
    const int xi0 = __float_as_int(rx0), xi1 = __float_as_int(rx1);
    float p0 = 0.f, p1 = 0.f, p2 = 0.f, p3 = 0.f;
#pragma unroll
    for (int d0 = 0; d0 < 64; d0 += 2) {
      float a0 = RL((float&)xi0, d0);
      float a1 = RL((float&)xi0, d0 + 1);
      float c0 = RL((float&)xi1, d0);
      float c1 = RL((float&)xi1, d0 + 1);
      p0 += a0 * w[d0];
      p1 += a1 * w[d0 + 1];
      p2 += c0 * w[64 + d0];
      p3 += c1 * w[64 + d0 + 1];
    }
    if (lane < 32) {
      float di = dinv[r];
      h2p[(size_t)r * 32 + col] = ((p0 + p1) + (p2 + p3)) * di;
    }
  }
}

// ---------------- gather layer 2 ----------------

__global__ __launch_bounds__(256) void k_gather2(const int* __restrict__ row, const int* __restrict__ cnt,
                                                 const int* __restrict__ esrc, const float* __restrict__ h2p,
                                                 const float* __restrict__ dinv, float* __restrict__ x2, int N) {
  const int lane = threadIdx.x & 63;
  const int node = RFL(blockIdx.x * 4 + (threadIdx.x >> 6));
  if (node >= N) return;
  const int q = lane >> 3, f4 = lane & 7;
  const int rs = RFL(row[node]);
  const int ne = RFL(cnt[node]);
  const float di = dinv[node];
  const float4* __restrict__ hv = (const float4*)h2p;
  float a0 = 0.f, a1 = 0.f, a2 = 0.f, a3 = 0.f;
  int j = q;
  for (; j + 9 <= ne; j += 16) {
    int s0 = esrc[rs + j], s1 = esrc[rs + j + 8];
    float4 v0 = hv[(size_t)s0 * 8 + f4];
    float4 v1 = hv[(size_t)s1 * 8 + f4];
    a0 += v0.x + v1.x;
    a1 += v0.y + v1.y;
    a2 += v0.z + v1.z;
    a3 += v0.w + v1.w;
  }
  for (; j < ne; j += 8) {
    int s = esrc[rs + j];
    float4 v = hv[(size_t)s * 8 + f4];
    a0 += v.x; a1 += v.y; a2 += v.z; a3 += v.w;
  }
#pragma unroll
  for (int off = 8; off <= 32; off <<= 1) {
    a0 += __shfl_xor(a0, off, 64);
    a1 += __shfl_xor(a1, off, 64);
    a2 += __shfl_xor(a2, off, 64);
    a3 += __shfl_xor(a3, off, 64);
  }
  if (q == 0) {
    float4 sv = hv[(size_t)node * 8 + f4];
    float4 o;
    o.x = (a0 + sv.x * di) * di;
    o.y = (a1 + sv.y * di) * di;
    o.z = (a2 + sv.z * di) * di;
    o.w = (a3 + sv.w * di) * di;
    ((float4*)x2)[(size_t)node * 8 + f4] = o;
  }
}

// ---------------- query MLP ----------------

__global__ __launch_bounds__(256) void k_mlp(const int* __restrict__ qidx, const float* __restrict__ x2,
                                             const float* __restrict__ b2, const float* __restrict__ Wm1,
                                             const float* __restrict__ bm1, const float* __restrict__ Wm2,
                                             const float* __restrict__ bm2, float* __restrict__ out, int B) {
  int t = blockIdx.x * 256 + threadIdx.x;
  if (t >= B) return;
  int n = qidx[t];
  float qv[32];
#pragma unroll
  for (int k = 0; k < 32; ++k) qv[k] = fmaxf(x2[(size_t)n * 32 + k] + b2[k], 0.f);
  float acc = bm2[0];
  for (int j = 0; j < 64; ++j) {
    float h = bm1[j];
#pragma unroll
    for (int k = 0; k < 32; ++k) h += qv[k] * Wm1[k * 64 + j];
    acc += fmaxf(h, 0.f) * Wm2[j];
  }
  out[t] = acc;
}

// ---------------- launcher ----------------

extern "C" void kernel_launch(void* const* d_in, const int* in_sizes, int n_in,
                              void* d_out, int out_size, void* d_ws, size_t ws_size,
                              hipStream_t stream) {
  const float* X    = (const float*)d_in[0];
  const int*   mask = (const int*)d_in[1];
  const int*   ei   = (const int*)d_in[2];
  const int*   qidx = (const int*)d_in[3];
  const float* WE   = (const float*)d_in[4];
  const float* bE   = (const float*)d_in[5];
  const float* WA   = (const float*)d_in[6];
  const float* bA   = (const float*)d_in[7];
  const float* Wout = (const float*)d_in[8];
  const float* bout = (const float*)d_in[9];
  const float* W1   = (const float*)d_in[10];
  const float* b1   = (const float*)d_in[11];
  const float* W2   = (const float*)d_in[12];
  const float* b2   = (const float*)d_in[13];
  const float* Wm1  = (const float*)d_in[14];
  const float* bm1  = (const float*)d_in[15];
  const float* Wm2  = (const float*)d_in[16];
  const float* bm2  = (const float*)d_in[17];

  const int N = in_sizes[1] / 20;
  const int E = in_sizes[2] / 2;
  const int B = in_sizes[3];
  const int* src  = ei;
  const int* dstp = ei + E;

  const size_t Na = ((size_t)N + 63) & ~(size_t)63;
  const size_t Ea = ((size_t)E + 63) & ~(size_t)63;
  const int P = (N + 255) / 256;
  const size_t Pa = ((size_t)P + 63) & ~(size_t)63;

  float* ws      = (float*)d_ws;
  float* dinv    = ws;                       // N
  int*   cnt     = (int*)(dinv + Na);        // N
  int*   rowp    = cnt + Na;                 // N
  int*   cursor  = rowp + Na;                // N
  int*   partial = cursor + Na;              // P
  int*   esrc    = partial + Pa;             // E
  float* Wc      = (float*)(esrc + Ea);      // 8192
  float* bc      = Wc + 8192;                // 128
  float* pz      = bc + 128;                 // N*64
  float* h1p     = pz + (size_t)N * 64;      // N*128
  float* x1      = h1p + (size_t)N * 128;    // N*128
  float* h2p     = pz;                       // reuse pz (dead after gemm1): N*32
  float* x2      = pz + (size_t)N * 32;      // N*32

  const int nb = (N + 255) / 256;
  const int nw4 = (N + 3) / 4;

  k_zero<<<nb, 256, 0, stream>>>(cnt, N);
  k_count<<<1024, 256, 0, stream>>>(dstp, cnt, E);
  k_scan1<<<P, 256, 0, stream>>>(cnt, rowp, partial, N);
  k_scan2<<<1, 256, 0, stream>>>(partial, P);
  k_scan3<<<P, 256, 0, stream>>>(rowp, partial, cursor, cnt, dinv, N);
  k_edge_fill<<<1024, 256, 0, stream>>>(src, dstp, cursor, esrc, E);
  k_wc<<<33, 256, 0, stream>>>(Wout, bout, W1, Wc, bc);
  k_pool<<<nw4, 256, 0, stream>>>(X, mask, WE, bE, WA, bA, pz, N);
  k_gemm1<<<1024, 256, 0, stream>>>(pz, Wc, bc, dinv, h1p, N);
  k_gather1<<<nw4, 256, 0, stream>>>(rowp, cnt, esrc, h1p, dinv, x1, N);
  k_gemm2<<<1024, 256, 0, stream>>>(x1, b1, W2, dinv, h2p, N);
  k_gather2<<<nw4, 256, 0, stream>>>(rowp, cnt, esrc, h2p, dinv, x2, N);
  k_mlp<<<(B + 255) / 256, 256, 0, stream>>>(qidx, x2, b2, Wm1, bm1, Wm2, bm2, (float*)d_out, B);
}

// Round 10
// 599.475 us; speedup vs baseline: 1.3237x; 1.0986x over previous
//
#include <hip/hip_runtime.h>
#include <math.h>

#define RFL(x) __builtin_amdgcn_readfirstlane(x)
#define RL(x, l) __int_as_float(__builtin_amdgcn_readlane(__float_as_int(x), (l)))

typedef __attribute__((ext_vector_type(8))) short bf16x8;
typedef __attribute__((ext_vector_type(4))) float f32x4;

__device__ inline unsigned short bf16_rne(float f) {
  unsigned u = __float_as_uint(f);
  u += 0x7FFFu + ((u >> 16) & 1u);
  return (unsigned short)(u >> 16);
}

// ---------------- degree histogram (int) ----------------

__global__ __launch_bounds__(256) void k_zero(int* p, int n) {
  int t = blockIdx.x * 256 + threadIdx.x;
  if (t < n) p[t] = 0;
}

__global__ __launch_bounds__(256) void k_count(const int* __restrict__ dst, int* cnt, int E) {
  int stride = gridDim.x * blockDim.x;
  for (int e = blockIdx.x * blockDim.x + threadIdx.x; e < E; e += stride)
    atomicAdd(&cnt[dst[e]], 1);
}

// ---------------- exclusive scan: cnt -> row_start ----------------

__global__ __launch_bounds__(256) void k_scan1(const int* __restrict__ cnt, int* __restrict__ row,
                                               int* __restrict__ partial, int N) {
  __shared__ int sm[256];
  int t = threadIdx.x, g = blockIdx.x * 256 + t;
  int v = (g < N) ? cnt[g] : 0;
  sm[t] = v;
  __syncthreads();
#pragma unroll
  for (int off = 1; off < 256; off <<= 1) {
    int x = 0;
    if (t >= off) x = sm[t - off];
    __syncthreads();
    if (t >= off) sm[t] += x;
    __syncthreads();
  }
  if (g < N) row[g] = sm[t] - v;  // exclusive within block
  if (t == 255) partial[blockIdx.x] = sm[255];
}

__global__ __launch_bounds__(256) void k_scan2(int* __restrict__ partial, int P) {
  __shared__ int sm[256];
  int t = threadIdx.x;
  int carry = 0;
  for (int base = 0; base < P; base += 256) {
    int idx = base + t;
    int v = (idx < P) ? partial[idx] : 0;
    sm[t] = v;
    __syncthreads();
#pragma unroll
    for (int off = 1; off < 256; off <<= 1) {
      int x = 0;
      if (t >= off) x = sm[t - off];
      __syncthreads();
      if (t >= off) sm[t] += x;
      __syncthreads();
    }
    if (idx < P) partial[idx] = carry + sm[t] - v;  // exclusive
    int tot = sm[255];
    __syncthreads();
    carry += tot;
  }
}

// scan3 + dinv fused
__global__ __launch_bounds__(256) void k_scan3(int* __restrict__ row, const int* __restrict__ partial,
                                               int* __restrict__ cursor, const int* __restrict__ cnt,
                                               float* __restrict__ dinv, int N) {
  int g = blockIdx.x * 256 + threadIdx.x;
  if (g < N) {
    int v = row[g] + partial[blockIdx.x];
    row[g] = v;
    cursor[g] = v;
    dinv[g] = rsqrtf((float)cnt[g] + 1.0f);  // +1 self-loop
  }
}

// ---------------- edge placement: dst-sorted src ----------------

__global__ __launch_bounds__(256) void k_edge_fill(const int* __restrict__ src, const int* __restrict__ dst,
                                                   int* __restrict__ cursor, int* __restrict__ esrc, int E) {
  int stride = gridDim.x * blockDim.x;
  for (int e = blockIdx.x * blockDim.x + threadIdx.x; e < E; e += stride) {
    int s = src[e], d = dst[e];
    int pos = atomicAdd(&cursor[d], 1);
    esrc[pos] = s;
  }
}

// ---------------- W_c = W_out @ W1, b_c = b_out @ W1 ----------------

__global__ __launch_bounds__(256) void k_wc(const float* __restrict__ Wout, const float* __restrict__ bout,
                                            const float* __restrict__ W1, float* __restrict__ Wc,
                                            float* __restrict__ bc) {
  int t = blockIdx.x * 256 + threadIdx.x;
  if (t >= 65 * 128) return;
  int h = t >> 7, o = t & 127;
  const float* row = (h < 64) ? (Wout + h * 128) : bout;
  float a = 0.f;
  for (int d = 0; d < 128; ++d) a += row[d] * W1[d * 128 + o];
  if (h < 64) Wc[h * 128 + o] = a;
  else bc[o] = a;
}

// ---------------- attention pooling via MFMA (split-bf16) ----------------
// Block = 256 thr / 4 waves, owns 80 rows = 4 nodes.
// R10 changes vs R9: (1) all 10 X float4 loads issued into regs BEFORE any
// dependent convert (one HBM latency per block, not ten); WE B-frag loads fill
// the shadow. (2) zt aliases Xh (dead after MFMA; barrier-separated) -> LDS
// 67->45.6KB -> 3 blocks/CU via __launch_bounds__(256,3).

__global__ __launch_bounds__(256, 3) void k_pool(const float* __restrict__ X, const int* __restrict__ mask,
                                                 const float* __restrict__ WE, const float* __restrict__ bE,
                                                 const float* __restrict__ WA, const float* __restrict__ bA,
                                                 float* __restrict__ pz, int N) {
  __shared__ __align__(16) unsigned short Xh[80][136];
  __shared__ __align__(16) unsigned short Xl[80][136];
  __shared__ float scorep[80][4];
  __shared__ float sco[80];
  __shared__ float parr[80];
  __shared__ float wgtA[80];
  float* zt = (float*)&Xh[0][0];  // alias: 80*68 f32 = 21760B = sizeof(Xh)

  const int t = threadIdx.x;
  const int lane = t & 63;
  const int wv = t >> 6;     // wave 0..3 = col tile
  const int cb = wv * 16;
  const int l16 = lane & 15;
  const int lg = lane >> 4;  // 0..3

  const long long totRows = (long long)N * 20;
  const long long rowBase = (long long)blockIdx.x * 80;

  // ---- phase 1: issue ALL X tile loads into regs (independent, back-to-back) ----
  float4 xv[10];
#pragma unroll
  for (int q = 0; q < 10; ++q) {
    int idx = q * 256 + t;  // float4 index in 80x128 tile
    int r = idx >> 5, kq = idx & 31;
    long long rr = rowBase + r;
    if (rr >= totRows) rr = totRows - 1;
    xv[q] = *(const float4*)(X + rr * 128 + kq * 4);
  }

  // ---- phase 2: B fragments (WE col-tile) in regs, hi/lo (fills X-load shadow) ----
  bf16x8 bh[4], bl[4];
#pragma unroll
  for (int kk = 0; kk < 4; ++kk) {
    union { bf16x8 v; unsigned short s[8]; } uh, ul;
#pragma unroll
    for (int i = 0; i < 8; ++i) {
      int k = kk * 32 + lg * 8 + i;
      float w = WE[k * 64 + cb + l16];
      unsigned short h = bf16_rne(w);
      uh.s[i] = h;
      ul.s[i] = bf16_rne(w - __uint_as_float((unsigned)h << 16));
    }
    bh[kk] = uh.v;
    bl[kk] = ul.v;
  }

  // ---- phase 3: convert + LDS write ----
#pragma unroll
  for (int q = 0; q < 10; ++q) {
    int idx = q * 256 + t;
    int r = idx >> 5, kq = idx & 31;
    const float4 v = xv[q];
    unsigned short h0 = bf16_rne(v.x), h1 = bf16_rne(v.y), h2 = bf16_rne(v.z), h3 = bf16_rne(v.w);
    float f0 = __uint_as_float((unsigned)h0 << 16);
    float f1 = __uint_as_float((unsigned)h1 << 16);
    float f2 = __uint_as_float((unsigned)h2 << 16);
    float f3 = __uint_as_float((unsigned)h3 << 16);
    *(ushort4*)&Xh[r][kq * 4] = make_ushort4(h0, h1, h2, h3);
    *(ushort4*)&Xl[r][kq * 4] = make_ushort4(bf16_rne(v.x - f0), bf16_rne(v.y - f1),
                                             bf16_rne(v.z - f2), bf16_rne(v.w - f3));
  }
  __syncthreads();

  // ---- MFMA: Z[80][16 cols of this wave] ----
  f32x4 acc[5];
#pragma unroll
  for (int rt = 0; rt < 5; ++rt) acc[rt] = (f32x4){0.f, 0.f, 0.f, 0.f};
#pragma unroll
  for (int rt = 0; rt < 5; ++rt) {
    const int rl = rt * 16 + l16;
#pragma unroll
    for (int kk = 0; kk < 4; ++kk) {
      const int ko = kk * 32 + lg * 8;
      bf16x8 ah = *(const bf16x8*)&Xh[rl][ko];
      bf16x8 al = *(const bf16x8*)&Xl[rl][ko];
      acc[rt] = __builtin_amdgcn_mfma_f32_16x16x32_bf16(ah, bh[kk], acc[rt], 0, 0, 0);
      acc[rt] = __builtin_amdgcn_mfma_f32_16x16x32_bf16(ah, bl[kk], acc[rt], 0, 0, 0);
      acc[rt] = __builtin_amdgcn_mfma_f32_16x16x32_bf16(al, bh[kk], acc[rt], 0, 0, 0);
    }
  }

  // ---- relu + per-row score partials (this wave's 16 cols) ----
  const float bEv = bE[cb + l16];
  const float WAv = WA[cb + l16];
#pragma unroll
  for (int rt = 0; rt < 5; ++rt) {
#pragma unroll
    for (int j = 0; j < 4; ++j) {
      float z = fmaxf(acc[rt][j] + bEv, 0.f);
      acc[rt][j] = z;
      float v = z * WAv;
      v += __shfl_xor(v, 1, 64);
      v += __shfl_xor(v, 2, 64);
      v += __shfl_xor(v, 4, 64);
      v += __shfl_xor(v, 8, 64);
      if (l16 == 0) scorep[rt * 16 + lg * 4 + j][wv] = v;
    }
  }
  __syncthreads();

  // ---- softmax over each node's 20 rows ----
  const float NEG = -3.0e38f;
  if (t < 80) {
    float4 sp = *(const float4*)scorep[t];
    float sc = sp.x + sp.y + sp.z + sp.w + bA[0];
    int node_l = t / 20, s_in = t - node_l * 20;
    long long node = (long long)blockIdx.x * 4 + node_l;
    int mk = (node < N) ? mask[node * 20 + s_in] : 0;
    if (mk == 0) sc = NEG;
    sco[t] = sc;
  }
  __syncthreads();
  if (t < 80) {
    int base = (t / 20) * 20;
    float mx = NEG;
#pragma unroll
    for (int i = 0; i < 20; ++i) mx = fmaxf(mx, sco[base + i]);
    float sc = sco[t];
    parr[t] = (sc <= -1.0e38f) ? 0.f : __expf(sc - mx);
  }
  __syncthreads();
  if (t < 80) {
    int base = (t / 20) * 20;
    float den = 0.f;
#pragma unroll
    for (int i = 0; i < 20; ++i) den += parr[base + i];
    wgtA[t] = parr[t] / fmaxf(den, 1e-37f);
  }
  __syncthreads();  // also: all waves past MFMA reads -> Xh reusable as zt

  // ---- weighted z -> LDS (zt aliases Xh) ----
#pragma unroll
  for (int rt = 0; rt < 5; ++rt) {
#pragma unroll
    for (int j = 0; j < 4; ++j) {
      int row = rt * 16 + lg * 4 + j;
      zt[row * 68 + cb + l16] = acc[rt][j] * wgtA[row];
    }
  }
  __syncthreads();

  // ---- pooled[n][col] = sum over 20 rows; coalesced store ----
  {
    int n = t >> 6, col = t & 63;
    float s = 0.f;
#pragma unroll
    for (int i = 0; i < 20; ++i) s += zt[(n * 20 + i) * 68 + col];
    long long node = (long long)blockIdx.x * 4 + n;
    if (node < N) pz[node * 64 + col] = s;
  }
}

// ---------------- h1p = (pz @ Wc + bc) * dinv[r] ----------------

__global__ __launch_bounds__(256, 2) void k_gemm1(const float* __restrict__ pz, const float* __restrict__ Wc,
                                                  const float* __restrict__ bc, const float* __restrict__ dinv,
                                                  float* __restrict__ h1p, int N) {
  const int lane = threadIdx.x & 63;
  float w0[64], w1[64];
#pragma unroll
  for (int d = 0; d < 64; ++d) {
    w0[d] = Wc[d * 128 + lane];
    w1[d] = Wc[d * 128 + 64 + lane];
  }
  const float b0 = bc[lane], b1v = bc[64 + lane];
  const int nw = (gridDim.x * blockDim.x) >> 6;
  const int w_id = (blockIdx.x * blockDim.x + threadIdx.x) >> 6;
  for (int r = w_id; r < N; r += nw) {
    const float xv = pz[(size_t)r * 64 + lane];
    const int xi = __float_as_int(xv);
    float p0 = 0.f, p1 = 0.f, p2 = 0.f, p3 = 0.f;
#pragma unroll
    for (int d0 = 0; d0 < 64; d0 += 2) {
      float a0 = RL((float&)xi, d0);
      float a1 = RL((float&)xi, d0 + 1);
      p0 += a0 * w0[d0];
      p1 += a0 * w1[d0];
      p2 += a1 * w0[d0 + 1];
      p3 += a1 * w1[d0 + 1];
    }
    float di = dinv[r];
    size_t o = (size_t)r * 128 + lane;
    h1p[o] = (b0 + p0 + p2) * di;
    h1p[o + 64] = (b1v + p1 + p3) * di;
  }
}

// ---------------- gather layer 1 ----------------

__global__ __launch_bounds__(256) void k_gather1(const int* __restrict__ row, const int* __restrict__ cnt,
                                                 const int* __restrict__ esrc, const float* __restrict__ h1p,
                                                 const float* __restrict__ dinv, float* __restrict__ x1, int N) {
  const int lane = threadIdx.x & 63;
  const int node = RFL(blockIdx.x * 4 + (threadIdx.x >> 6));
  if (node >= N) return;
  const int half = lane >> 5, f4 = lane & 31;
  const int rs = RFL(row[node]);
  const int ne = RFL(cnt[node]);
  const float di = dinv[node];
  const float4* __restrict__ hv = (const float4*)h1p;
  float a0 = 0.f, a1 = 0.f, a2 = 0.f, a3 = 0.f;
  int j = half;
  for (; j + 7 <= ne; j += 8) {
    int s0 = esrc[rs + j], s1 = esrc[rs + j + 2], s2 = esrc[rs + j + 4], s3 = esrc[rs + j + 6];
    float4 v0 = hv[(size_t)s0 * 32 + f4];
    float4 v1 = hv[(size_t)s1 * 32 + f4];
    float4 v2 = hv[(size_t)s2 * 32 + f4];
    float4 v3 = hv[(size_t)s3 * 32 + f4];
    a0 += v0.x + v1.x + v2.x + v3.x;
    a1 += v0.y + v1.y + v2.y + v3.y;
    a2 += v0.z + v1.z + v2.z + v3.z;
    a3 += v0.w + v1.w + v2.w + v3.w;
  }
  for (; j < ne; j += 2) {
    int s = esrc[rs + j];
    float4 v = hv[(size_t)s * 32 + f4];
    a0 += v.x; a1 += v.y; a2 += v.z; a3 += v.w;
  }
  a0 += __shfl_xor(a0, 32, 64);
  a1 += __shfl_xor(a1, 32, 64);
  a2 += __shfl_xor(a2, 32, 64);
  a3 += __shfl_xor(a3, 32, 64);
  if (half == 0) {
    float4 sv = hv[(size_t)node * 32 + f4];
    float4 o;
    o.x = (a0 + sv.x * di) * di;
    o.y = (a1 + sv.y * di) * di;
    o.z = (a2 + sv.z * di) * di;
    o.w = (a3 + sv.w * di) * di;
    ((float4*)x1)[(size_t)node * 32 + f4] = o;
  }
}

// ---------------- h2p = (relu(x1 + b1) @ W2) * dinv[r] ----------------

__global__ __launch_bounds__(256, 2) void k_gemm2(const float* __restrict__ x1, const float* __restrict__ b1,
                                                  const float* __restrict__ W2, const float* __restrict__ dinv,
                                                  float* __restrict__ h2p, int N) {
  const int lane = threadIdx.x & 63;
  const int col = lane & 31;
  float w[128];
#pragma unroll
  for (int d = 0; d < 128; ++d) w[d] = W2[d * 32 + col];
  const float bb0 = b1[lane], bb1 = b1[64 + lane];
  const int nw = (gridDim.x * blockDim.x) >> 6;
  const int w_id = (blockIdx.x * blockDim.x + threadIdx.x) >> 6;
  for (int r = w_id; r < N; r += nw) {
    float rx0 = fmaxf(x1[(size_t)r * 128 + lane] + bb0, 0.f);
    float rx1 = fmaxf(x1[(size_t)r * 128 + 64 + lane] + bb1, 0.f);
    const int xi0 = __float_as_int(rx0), xi1 = __float_as_int(rx1);
    float p0 = 0.f, p1 = 0.f, p2 = 0.f, p3 = 0.f;
#pragma unroll
    for (int d0 = 0; d0 < 64; d0 += 2) {
      float a0 = RL((float&)xi0, d0);
      float a1 = RL((float&)xi0, d0 + 1);
      float c0 = RL((float&)xi1, d0);
      float c1 = RL((float&)xi1, d0 + 1);
      p0 += a0 * w[d0];
      p1 += a1 * w[d0 + 1];
      p2 += c0 * w[64 + d0];
      p3 += c1 * w[64 + d0 + 1];
    }
    if (lane < 32) {
      float di = dinv[r];
      h2p[(size_t)r * 32 + col] = ((p0 + p1) + (p2 + p3)) * di;
    }
  }
}

// ---------------- gather layer 2 ----------------

__global__ __launch_bounds__(256) void k_gather2(const int* __restrict__ row, const int* __restrict__ cnt,
                                                 const int* __restrict__ esrc, const float* __restrict__ h2p,
                                                 const float* __restrict__ dinv, float* __restrict__ x2, int N) {
  const int lane = threadIdx.x & 63;
  const int node = RFL(blockIdx.x * 4 + (threadIdx.x >> 6));
  if (node >= N) return;
  const int q = lane >> 3, f4 = lane & 7;
  const int rs = RFL(row[node]);
  const int ne = RFL(cnt[node]);
  const float di = dinv[node];
  const float4* __restrict__ hv = (const float4*)h2p;
  float a0 = 0.f, a1 = 0.f, a2 = 0.f, a3 = 0.f;
  int j = q;
  for (; j + 9 <= ne; j += 16) {
    int s0 = esrc[rs + j], s1 = esrc[rs + j + 8];
    float4 v0 = hv[(size_t)s0 * 8 + f4];
    float4 v1 = hv[(size_t)s1 * 8 + f4];
    a0 += v0.x + v1.x;
    a1 += v0.y + v1.y;
    a2 += v0.z + v1.z;
    a3 += v0.w + v1.w;
  }
  for (; j < ne; j += 8) {
    int s = esrc[rs + j];
    float4 v = hv[(size_t)s * 8 + f4];
    a0 += v.x; a1 += v.y; a2 += v.z; a3 += v.w;
  }
#pragma unroll
  for (int off = 8; off <= 32; off <<= 1) {
    a0 += __shfl_xor(a0, off, 64);
    a1 += __shfl_xor(a1, off, 64);
    a2 += __shfl_xor(a2, off, 64);
    a3 += __shfl_xor(a3, off, 64);
  }
  if (q == 0) {
    float4 sv = hv[(size_t)node * 8 + f4];
    float4 o;
    o.x = (a0 + sv.x * di) * di;
    o.y = (a1 + sv.y * di) * di;
    o.z = (a2 + sv.z * di) * di;
    o.w = (a3 + sv.w * di) * di;
    ((float4*)x2)[(size_t)node * 8 + f4] = o;
  }
}

// ---------------- query MLP ----------------

__global__ __launch_bounds__(256) void k_mlp(const int* __restrict__ qidx, const float* __restrict__ x2,
                                             const float* __restrict__ b2, const float* __restrict__ Wm1,
                                             const float* __restrict__ bm1, const float* __restrict__ Wm2,
                                             const float* __restrict__ bm2, float* __restrict__ out, int B) {
  int t = blockIdx.x * 256 + threadIdx.x;
  if (t >= B) return;
  int n = qidx[t];
  float qv[32];
#pragma unroll
  for (int k = 0; k < 32; ++k) qv[k] = fmaxf(x2[(size_t)n * 32 + k] + b2[k], 0.f);
  float acc = bm2[0];
  for (int j = 0; j < 64; ++j) {
    float h = bm1[j];
#pragma unroll
    for (int k = 0; k < 32; ++k) h += qv[k] * Wm1[k * 64 + j];
    acc += fmaxf(h, 0.f) * Wm2[j];
  }
  out[t] = acc;
}

// ---------------- launcher ----------------

extern "C" void kernel_launch(void* const* d_in, const int* in_sizes, int n_in,
                              void* d_out, int out_size, void* d_ws, size_t ws_size,
                              hipStream_t stream) {
  const float* X    = (const float*)d_in[0];
  const int*   mask = (const int*)d_in[1];
  const int*   ei   = (const int*)d_in[2];
  const int*   qidx = (const int*)d_in[3];
  const float* WE   = (const float*)d_in[4];
  const float* bE   = (const float*)d_in[5];
  const float* WA   = (const float*)d_in[6];
  const float* bA   = (const float*)d_in[7];
  const float* Wout = (const float*)d_in[8];
  const float* bout = (const float*)d_in[9];
  const float* W1   = (const float*)d_in[10];
  const float* b1   = (const float*)d_in[11];
  const float* W2   = (const float*)d_in[12];
  const float* b2   = (const float*)d_in[13];
  const float* Wm1  = (const float*)d_in[14];
  const float* bm1  = (const float*)d_in[15];
  const float* Wm2  = (const float*)d_in[16];
  const float* bm2  = (const float*)d_in[17];

  const int N = in_sizes[1] / 20;
  const int E = in_sizes[2] / 2;
  const int B = in_sizes[3];
  const int* src  = ei;
  const int* dstp = ei + E;

  const size_t Na = ((size_t)N + 63) & ~(size_t)63;
  const size_t Ea = ((size_t)E + 63) & ~(size_t)63;
  const int P = (N + 255) / 256;
  const size_t Pa = ((size_t)P + 63) & ~(size_t)63;

  float* ws      = (float*)d_ws;
  float* dinv    = ws;                       // N
  int*   cnt     = (int*)(dinv + Na);        // N
  int*   rowp    = cnt + Na;                 // N
  int*   cursor  = rowp + Na;                // N
  int*   partial = cursor + Na;              // P
  int*   esrc    = partial + Pa;             // E
  float* Wc      = (float*)(esrc + Ea);      // 8192
  float* bc      = Wc + 8192;                // 128
  float* pz      = bc + 128;                 // N*64
  float* h1p     = pz + (size_t)N * 64;      // N*128
  float* x1      = h1p + (size_t)N * 128;    // N*128
  float* h2p     = pz;                       // reuse pz (dead after gemm1): N*32
  float* x2      = pz + (size_t)N * 32;      // N*32

  const int nb = (N + 255) / 256;
  const int nw4 = (N + 3) / 4;

  k_zero<<<nb, 256, 0, stream>>>(cnt, N);
  k_count<<<1024, 256, 0, stream>>>(dstp, cnt, E);
  k_scan1<<<P, 256, 0, stream>>>(cnt, rowp, partial, N);
  k_scan2<<<1, 256, 0, stream>>>(partial, P);
  k_scan3<<<P, 256, 0, stream>>>(rowp, partial, cursor, cnt, dinv, N);
  k_edge_fill<<<1024, 256, 0, stream>>>(src, dstp, cursor, esrc, E);
  k_wc<<<33, 256, 0, stream>>>(Wout, bout, W1, Wc, bc);
  k_pool<<<nw4, 256, 0, stream>>>(X, mask, WE, bE, WA, bA, pz, N);
  k_gemm1<<<1024, 256, 0, stream>>>(pz, Wc, bc, dinv, h1p, N);
  k_gather1<<<nw4, 256, 0, stream>>>(rowp, cnt, esrc, h1p, dinv, x1, N);
  k_gemm2<<<1024, 256, 0, stream>>>(x1, b1, W2, dinv, h2p, N);
  k_gather2<<<nw4, 256, 0, stream>>>(rowp, cnt, esrc, h2p, dinv, x2, N);
  k_mlp<<<(B + 255) / 256, 256, 0, stream>>>(qidx, x2, b2, Wm1, bm1, Wm2, bm2, (float*)d_out, B);
}

// Round 11
// 571.990 us; speedup vs baseline: 1.3873x; 1.0481x over previous
//
#include <hip/hip_runtime.h>
#include <math.h>

#define RFL(x) __builtin_amdgcn_readfirstlane(x)
#define RL(x, l) __int_as_float(__builtin_amdgcn_readlane(__float_as_int(x), (l)))

typedef __attribute__((ext_vector_type(8))) short bf16x8;
typedef __attribute__((ext_vector_type(4))) float f32x4;

__device__ inline unsigned short bf16_rne(float f) {
  unsigned u = __float_as_uint(f);
  u += 0x7FFFu + ((u >> 16) & 1u);
  return (unsigned short)(u >> 16);
}

// ---------------- degree histogram (int) ----------------

__global__ __launch_bounds__(256) void k_zero(int* p, int n) {
  int t = blockIdx.x * 256 + threadIdx.x;
  if (t < n) p[t] = 0;
}

__global__ __launch_bounds__(256) void k_count(const int* __restrict__ dst, int* cnt, int E) {
  int stride = gridDim.x * blockDim.x;
  for (int e = blockIdx.x * blockDim.x + threadIdx.x; e < E; e += stride)
    atomicAdd(&cnt[dst[e]], 1);
}

// ---------------- exclusive scan: cnt -> row_start ----------------

__global__ __launch_bounds__(256) void k_scan1(const int* __restrict__ cnt, int* __restrict__ row,
                                               int* __restrict__ partial, int N) {
  __shared__ int sm[256];
  int t = threadIdx.x, g = blockIdx.x * 256 + t;
  int v = (g < N) ? cnt[g] : 0;
  sm[t] = v;
  __syncthreads();
#pragma unroll
  for (int off = 1; off < 256; off <<= 1) {
    int x = 0;
    if (t >= off) x = sm[t - off];
    __syncthreads();
    if (t >= off) sm[t] += x;
    __syncthreads();
  }
  if (g < N) row[g] = sm[t] - v;  // exclusive within block
  if (t == 255) partial[blockIdx.x] = sm[255];
}

__global__ __launch_bounds__(256) void k_scan2(int* __restrict__ partial, int P) {
  __shared__ int sm[256];
  int t = threadIdx.x;
  int carry = 0;
  for (int base = 0; base < P; base += 256) {
    int idx = base + t;
    int v = (idx < P) ? partial[idx] : 0;
    sm[t] = v;
    __syncthreads();
#pragma unroll
    for (int off = 1; off < 256; off <<= 1) {
      int x = 0;
      if (t >= off) x = sm[t - off];
      __syncthreads();
      if (t >= off) sm[t] += x;
      __syncthreads();
    }
    if (idx < P) partial[idx] = carry + sm[t] - v;  // exclusive
    int tot = sm[255];
    __syncthreads();
    carry += tot;
  }
}

// scan3 + dinv fused
__global__ __launch_bounds__(256) void k_scan3(int* __restrict__ row, const int* __restrict__ partial,
                                               int* __restrict__ cursor, const int* __restrict__ cnt,
                                               float* __restrict__ dinv, int N) {
  int g = blockIdx.x * 256 + threadIdx.x;
  if (g < N) {
    int v = row[g] + partial[blockIdx.x];
    row[g] = v;
    cursor[g] = v;
    dinv[g] = rsqrtf((float)cnt[g] + 1.0f);  // +1 self-loop
  }
}

// ---------------- edge placement: dst-sorted src ----------------

__global__ __launch_bounds__(256) void k_edge_fill(const int* __restrict__ src, const int* __restrict__ dst,
                                                   int* __restrict__ cursor, int* __restrict__ esrc, int E) {
  int stride = gridDim.x * blockDim.x;
  for (int e = blockIdx.x * blockDim.x + threadIdx.x; e < E; e += stride) {
    int s = src[e], d = dst[e];
    int pos = atomicAdd(&cursor[d], 1);
    esrc[pos] = s;
  }
}

// ---------------- W_c = W_out @ W1, b_c = b_out @ W1 ----------------

__global__ __launch_bounds__(256) void k_wc(const float* __restrict__ Wout, const float* __restrict__ bout,
                                            const float* __restrict__ W1, float* __restrict__ Wc,
                                            float* __restrict__ bc) {
  int t = blockIdx.x * 256 + threadIdx.x;
  if (t >= 65 * 128) return;
  int h = t >> 7, o = t & 127;
  const float* row = (h < 64) ? (Wout + h * 128) : bout;
  float a = 0.f;
  for (int d = 0; d < 128; ++d) a += row[d] * W1[d * 128 + o];
  if (h < 64) Wc[h * 128 + o] = a;
  else bc[o] = a;
}

// ---------------- attention pooling via MFMA (split-bf16), PERSISTENT+PIPELINED ----------------
// 768 blocks (3/CU) grid-stride over ~16 tiles of 80 rows (4 nodes) each.
// Per iteration: convert regs->LDS, barrier, ISSUE NEXT TILE'S LOADS, then
// MFMA + epilogue execute under the next-load latency. First-tile latency is
// paid once per block instead of once per tile.

__global__ __launch_bounds__(256, 3) void k_pool(const float* __restrict__ X, const int* __restrict__ mask,
                                                 const float* __restrict__ WE, const float* __restrict__ bE,
                                                 const float* __restrict__ WA, const float* __restrict__ bA,
                                                 float* __restrict__ pz, int N) {
  __shared__ __align__(16) unsigned short Xh[80][136];
  __shared__ __align__(16) unsigned short Xl[80][136];
  __shared__ float scorep[80][4];
  __shared__ float sco[80];
  __shared__ float parr[80];
  __shared__ float wgtA[80];
  float* zt = (float*)&Xh[0][0];  // alias: 80*68 f32 = 21760B = sizeof(Xh)

  const int t = threadIdx.x;
  const int lane = t & 63;
  const int wv = t >> 6;     // wave 0..3 = col tile
  const int cb = wv * 16;
  const int l16 = lane & 15;
  const int lg = lane >> 4;  // 0..3

  const long long totRows = (long long)N * 20;
  const int numTiles = (N + 3) / 4;

  // per-thread load coords within a tile
  const int r0 = t >> 5;            // rows r0, r0+8, ..., r0+72
  const int kq4 = (t & 31) * 4;     // float col base

  // ---- B fragments (WE col-tile) in regs, hi/lo: loaded once ----
  bf16x8 bh[4], bl[4];
#pragma unroll
  for (int kk = 0; kk < 4; ++kk) {
    union { bf16x8 v; unsigned short s[8]; } uh, ul;
#pragma unroll
    for (int i = 0; i < 8; ++i) {
      int k = kk * 32 + lg * 8 + i;
      float w = WE[k * 64 + cb + l16];
      unsigned short h = bf16_rne(w);
      uh.s[i] = h;
      ul.s[i] = bf16_rne(w - __uint_as_float((unsigned)h << 16));
    }
    bh[kk] = uh.v;
    bl[kk] = ul.v;
  }
  const float bEv = bE[cb + l16];
  const float WAv = WA[cb + l16];
  const float bAv = bA[0];
  const float NEG = -3.0e38f;

  int tile = blockIdx.x;
  if (tile >= numTiles) return;

  // ---- prefetch first tile ----
  float4 xv[10];
#pragma unroll
  for (int q = 0; q < 10; ++q) {
    long long rr = (long long)tile * 80 + r0 + q * 8;
    if (rr >= totRows) rr = totRows - 1;
    xv[q] = *(const float4*)(X + rr * 128 + kq4);
  }

  while (true) {
    // ---- convert current tile -> LDS ----
#pragma unroll
    for (int q = 0; q < 10; ++q) {
      const int r = r0 + q * 8;
      const float4 v = xv[q];
      unsigned short h0 = bf16_rne(v.x), h1 = bf16_rne(v.y), h2 = bf16_rne(v.z), h3 = bf16_rne(v.w);
      float f0 = __uint_as_float((unsigned)h0 << 16);
      float f1 = __uint_as_float((unsigned)h1 << 16);
      float f2 = __uint_as_float((unsigned)h2 << 16);
      float f3 = __uint_as_float((unsigned)h3 << 16);
      *(ushort4*)&Xh[r][kq4] = make_ushort4(h0, h1, h2, h3);
      *(ushort4*)&Xl[r][kq4] = make_ushort4(bf16_rne(v.x - f0), bf16_rne(v.y - f1),
                                            bf16_rne(v.z - f2), bf16_rne(v.w - f3));
    }
    __syncthreads();

    // ---- issue next tile's loads (latency hidden under MFMA+epilogue) ----
    const int nextTile = tile + gridDim.x;
    const bool hasNext = nextTile < numTiles;
    float4 xn[10];
    {
      const long long nb = (long long)(hasNext ? nextTile : tile) * 80;
#pragma unroll
      for (int q = 0; q < 10; ++q) {
        long long rr = nb + r0 + q * 8;
        if (rr >= totRows) rr = totRows - 1;
        xn[q] = *(const float4*)(X + rr * 128 + kq4);
      }
    }

    // ---- MFMA: Z[80][16 cols of this wave] ----
    f32x4 acc[5];
#pragma unroll
    for (int rt = 0; rt < 5; ++rt) acc[rt] = (f32x4){0.f, 0.f, 0.f, 0.f};
#pragma unroll
    for (int rt = 0; rt < 5; ++rt) {
      const int rl = rt * 16 + l16;
#pragma unroll
      for (int kk = 0; kk < 4; ++kk) {
        const int ko = kk * 32 + lg * 8;
        bf16x8 ah = *(const bf16x8*)&Xh[rl][ko];
        bf16x8 al = *(const bf16x8*)&Xl[rl][ko];
        acc[rt] = __builtin_amdgcn_mfma_f32_16x16x32_bf16(ah, bh[kk], acc[rt], 0, 0, 0);
        acc[rt] = __builtin_amdgcn_mfma_f32_16x16x32_bf16(ah, bl[kk], acc[rt], 0, 0, 0);
        acc[rt] = __builtin_amdgcn_mfma_f32_16x16x32_bf16(al, bh[kk], acc[rt], 0, 0, 0);
      }
    }

    // ---- relu + per-row score partials ----
#pragma unroll
    for (int rt = 0; rt < 5; ++rt) {
#pragma unroll
      for (int j = 0; j < 4; ++j) {
        float z = fmaxf(acc[rt][j] + bEv, 0.f);
        acc[rt][j] = z;
        float v = z * WAv;
        v += __shfl_xor(v, 1, 64);
        v += __shfl_xor(v, 2, 64);
        v += __shfl_xor(v, 4, 64);
        v += __shfl_xor(v, 8, 64);
        if (l16 == 0) scorep[rt * 16 + lg * 4 + j][wv] = v;
      }
    }
    __syncthreads();

    // ---- softmax over each node's 20 rows ----
    if (t < 80) {
      float4 sp = *(const float4*)scorep[t];
      float sc = sp.x + sp.y + sp.z + sp.w + bAv;
      int node_l = t / 20, s_in = t - node_l * 20;
      long long node = (long long)tile * 4 + node_l;
      int mk = (node < N) ? mask[node * 20 + s_in] : 0;
      if (mk == 0) sc = NEG;
      sco[t] = sc;
    }
    __syncthreads();
    if (t < 80) {
      int base = (t / 20) * 20;
      float mx = NEG;
#pragma unroll
      for (int i = 0; i < 20; ++i) mx = fmaxf(mx, sco[base + i]);
      float sc = sco[t];
      parr[t] = (sc <= -1.0e38f) ? 0.f : __expf(sc - mx);
    }
    __syncthreads();
    if (t < 80) {
      int base = (t / 20) * 20;
      float den = 0.f;
#pragma unroll
      for (int i = 0; i < 20; ++i) den += parr[base + i];
      wgtA[t] = parr[t] / fmaxf(den, 1e-37f);
    }
    __syncthreads();  // MFMA reads of Xh done -> reusable as zt

    // ---- weighted z -> LDS (zt aliases Xh) ----
#pragma unroll
    for (int rt = 0; rt < 5; ++rt) {
#pragma unroll
      for (int j = 0; j < 4; ++j) {
        int row = rt * 16 + lg * 4 + j;
        zt[row * 68 + cb + l16] = acc[rt][j] * wgtA[row];
      }
    }
    __syncthreads();

    // ---- pooled[n][col] = sum over 20 rows; coalesced store ----
    {
      int n = t >> 6, col = t & 63;
      float s = 0.f;
#pragma unroll
      for (int i = 0; i < 20; ++i) s += zt[(n * 20 + i) * 68 + col];
      long long node = (long long)tile * 4 + n;
      if (node < N) pz[node * 64 + col] = s;
    }

    if (!hasNext) break;
    __syncthreads();  // zt reads done before next iteration's Xh write
#pragma unroll
    for (int q = 0; q < 10; ++q) xv[q] = xn[q];
    tile = nextTile;
  }
}

// ---------------- h1p = (pz @ Wc + bc) * dinv[r] ----------------

__global__ __launch_bounds__(256, 2) void k_gemm1(const float* __restrict__ pz, const float* __restrict__ Wc,
                                                  const float* __restrict__ bc, const float* __restrict__ dinv,
                                                  float* __restrict__ h1p, int N) {
  const int lane = threadIdx.x & 63;
  float w0[64], w1[64];
#pragma unroll
  for (int d = 0; d < 64; ++d) {
    w0[d] = Wc[d * 128 + lane];
    w1[d] = Wc[d * 128 + 64 + lane];
  }
  const float b0 = bc[lane], b1v = bc[64 + lane];
  const int nw = (gridDim.x * blockDim.x) >> 6;
  const int w_id = (blockIdx.x * blockDim.x + threadIdx.x) >> 6;
  for (int r = w_id; r < N; r += nw) {
    const float xv = pz[(size_t)r * 64 + lane];
    const int xi = __float_as_int(xv);
    float p0 = 0.f, p1 = 0.f, p2 = 0.f, p3 = 0.f;
#pragma unroll
    for (int d0 = 0; d0 < 64; d0 += 2) {
      float a0 = RL((float&)xi, d0);
      float a1 = RL((float&)xi, d0 + 1);
      p0 += a0 * w0[d0];
      p1 += a0 * w1[d0];
      p2 += a1 * w0[d0 + 1];
      p3 += a1 * w1[d0 + 1];
    }
    float di = dinv[r];
    size_t o = (size_t)r * 128 + lane;
    h1p[o] = (b0 + p0 + p2) * di;
    h1p[o + 64] = (b1v + p1 + p3) * di;
  }
}

// ---------------- gather layer 1 ----------------

__global__ __launch_bounds__(256) void k_gather1(const int* __restrict__ row, const int* __restrict__ cnt,
                                                 const int* __restrict__ esrc, const float* __restrict__ h1p,
                                                 const float* __restrict__ dinv, float* __restrict__ x1, int N) {
  const int lane = threadIdx.x & 63;
  const int node = RFL(blockIdx.x * 4 + (threadIdx.x >> 6));
  if (node >= N) return;
  const int half = lane >> 5, f4 = lane & 31;
  const int rs = RFL(row[node]);
  const int ne = RFL(cnt[node]);
  const float di = dinv[node];
  const float4* __restrict__ hv = (const float4*)h1p;
  float a0 = 0.f, a1 = 0.f, a2 = 0.f, a3 = 0.f;
  int j = half;
  for (; j + 7 <= ne; j += 8) {
    int s0 = esrc[rs + j], s1 = esrc[rs + j + 2], s2 = esrc[rs + j + 4], s3 = esrc[rs + j + 6];
    float4 v0 = hv[(size_t)s0 * 32 + f4];
    float4 v1 = hv[(size_t)s1 * 32 + f4];
    float4 v2 = hv[(size_t)s2 * 32 + f4];
    float4 v3 = hv[(size_t)s3 * 32 + f4];
    a0 += v0.x + v1.x + v2.x + v3.x;
    a1 += v0.y + v1.y + v2.y + v3.y;
    a2 += v0.z + v1.z + v2.z + v3.z;
    a3 += v0.w + v1.w + v2.w + v3.w;
  }
  for (; j < ne; j += 2) {
    int s = esrc[rs + j];
    float4 v = hv[(size_t)s * 32 + f4];
    a0 += v.x; a1 += v.y; a2 += v.z; a3 += v.w;
  }
  a0 += __shfl_xor(a0, 32, 64);
  a1 += __shfl_xor(a1, 32, 64);
  a2 += __shfl_xor(a2, 32, 64);
  a3 += __shfl_xor(a3, 32, 64);
  if (half == 0) {
    float4 sv = hv[(size_t)node * 32 + f4];
    float4 o;
    o.x = (a0 + sv.x * di) * di;
    o.y = (a1 + sv.y * di) * di;
    o.z = (a2 + sv.z * di) * di;
    o.w = (a3 + sv.w * di) * di;
    ((float4*)x1)[(size_t)node * 32 + f4] = o;
  }
}

// ---------------- h2p = (relu(x1 + b1) @ W2) * dinv[r] ----------------

__global__ __launch_bounds__(256, 2) void k_gemm2(const float* __restrict__ x1, const float* __restrict__ b1,
                                                  const float* __restrict__ W2, const float* __restrict__ dinv,
                                                  float* __restrict__ h2p, int N) {
  const int lane = threadIdx.x & 63;
  const int col = lane & 31;
  float w[128];
#pragma unroll
  for (int d = 0; d < 128; ++d) w[d] = W2[d * 32 + col];
  const float bb0 = b1[lane], bb1 = b1[64 + lane];
  const int nw = (gridDim.x * blockDim.x) >> 6;
  const int w_id = (blockIdx.x * blockDim.x + threadIdx.x) >> 6;
  for (int r = w_id; r < N; r += nw) {
    float rx0 = fmaxf(x1[(size_t)r * 128 + lane] + bb0, 0.f);
    float rx1 = fmaxf(x1[(size_t)r * 128 + 64 + lane] + bb1, 0.f);
    const int xi0 = __float_as_int(rx0), xi1 = __float_as_int(rx1);
    float p0 = 0.f, p1 = 0.f, p2 = 0.f, p3 = 0.f;
#pragma unroll
    for (int d0 = 0; d0 < 64; d0 += 2) {
      float a0 = RL((float&)xi0, d0);
      float a1 = RL((float&)xi0, d0 + 1);
      float c0 = RL((float&)xi1, d0);
      float c1 = RL((float&)xi1, d0 + 1);
      p0 += a0 * w[d0];
      p1 += a1 * w[d0 + 1];
      p2 += c0 * w[64 + d0];
      p3 += c1 * w[64 + d0 + 1];
    }
    if (lane < 32) {
      float di = dinv[r];
      h2p[(size_t)r * 32 + col] = ((p0 + p1) + (p2 + p3)) * di;
    }
  }
}

// ---------------- gather layer 2 ----------------

__global__ __launch_bounds__(256) void k_gather2(const int* __restrict__ row, const int* __restrict__ cnt,
                                                 const int* __restrict__ esrc, const float* __restrict__ h2p,
                                                 const float* __restrict__ dinv, float* __restrict__ x2, int N) {
  const int lane = threadIdx.x & 63;
  const int node = RFL(blockIdx.x * 4 + (threadIdx.x >> 6));
  if (node >= N) return;
  const int q = lane >> 3, f4 = lane & 7;
  const int rs = RFL(row[node]);
  const int ne = RFL(cnt[node]);
  const float di = dinv[node];
  const float4* __restrict__ hv = (const float4*)h2p;
  float a0 = 0.f, a1 = 0.f, a2 = 0.f, a3 = 0.f;
  int j = q;
  for (; j + 9 <= ne; j += 16) {
    int s0 = esrc[rs + j], s1 = esrc[rs + j + 8];
    float4 v0 = hv[(size_t)s0 * 8 + f4];
    float4 v1 = hv[(size_t)s1 * 8 + f4];
    a0 += v0.x + v1.x;
    a1 += v0.y + v1.y;
    a2 += v0.z + v1.z;
    a3 += v0.w + v1.w;
  }
  for (; j < ne; j += 8) {
    int s = esrc[rs + j];
    float4 v = hv[(size_t)s * 8 + f4];
    a0 += v.x; a1 += v.y; a2 += v.z; a3 += v.w;
  }
#pragma unroll
  for (int off = 8; off <= 32; off <<= 1) {
    a0 += __shfl_xor(a0, off, 64);
    a1 += __shfl_xor(a1, off, 64);
    a2 += __shfl_xor(a2, off, 64);
    a3 += __shfl_xor(a3, off, 64);
  }
  if (q == 0) {
    float4 sv = hv[(size_t)node * 8 + f4];
    float4 o;
    o.x = (a0 + sv.x * di) * di;
    o.y = (a1 + sv.y * di) * di;
    o.z = (a2 + sv.z * di) * di;
    o.w = (a3 + sv.w * di) * di;
    ((float4*)x2)[(size_t)node * 8 + f4] = o;
  }
}

// ---------------- query MLP ----------------

__global__ __launch_bounds__(256) void k_mlp(const int* __restrict__ qidx, const float* __restrict__ x2,
                                             const float* __restrict__ b2, const float* __restrict__ Wm1,
                                             const float* __restrict__ bm1, const float* __restrict__ Wm2,
                                             const float* __restrict__ bm2, float* __restrict__ out, int B) {
  int t = blockIdx.x * 256 + threadIdx.x;
  if (t >= B) return;
  int n = qidx[t];
  float qv[32];
#pragma unroll
  for (int k = 0; k < 32; ++k) qv[k] = fmaxf(x2[(size_t)n * 32 + k] + b2[k], 0.f);
  float acc = bm2[0];
  for (int j = 0; j < 64; ++j) {
    float h = bm1[j];
#pragma unroll
    for (int k = 0; k < 32; ++k) h += qv[k] * Wm1[k * 64 + j];
    acc += fmaxf(h, 0.f) * Wm2[j];
  }
  out[t] = acc;
}

// ---------------- launcher ----------------

extern "C" void kernel_launch(void* const* d_in, const int* in_sizes, int n_in,
                              void* d_out, int out_size, void* d_ws, size_t ws_size,
                              hipStream_t stream) {
  const float* X    = (const float*)d_in[0];
  const int*   mask = (const int*)d_in[1];
  const int*   ei   = (const int*)d_in[2];
  const int*   qidx = (const int*)d_in[3];
  const float* WE   = (const float*)d_in[4];
  const float* bE   = (const float*)d_in[5];
  const float* WA   = (const float*)d_in[6];
  const float* bA   = (const float*)d_in[7];
  const float* Wout = (const float*)d_in[8];
  const float* bout = (const float*)d_in[9];
  const float* W1   = (const float*)d_in[10];
  const float* b1   = (const float*)d_in[11];
  const float* W2   = (const float*)d_in[12];
  const float* b2   = (const float*)d_in[13];
  const float* Wm1  = (const float*)d_in[14];
  const float* bm1  = (const float*)d_in[15];
  const float* Wm2  = (const float*)d_in[16];
  const float* bm2  = (const float*)d_in[17];

  const int N = in_sizes[1] / 20;
  const int E = in_sizes[2] / 2;
  const int B = in_sizes[3];
  const int* src  = ei;
  const int* dstp = ei + E;

  const size_t Na = ((size_t)N + 63) & ~(size_t)63;
  const size_t Ea = ((size_t)E + 63) & ~(size_t)63;
  const int P = (N + 255) / 256;
  const size_t Pa = ((size_t)P + 63) & ~(size_t)63;

  float* ws      = (float*)d_ws;
  float* dinv    = ws;                       // N
  int*   cnt     = (int*)(dinv + Na);        // N
  int*   rowp    = cnt + Na;                 // N
  int*   cursor  = rowp + Na;                // N
  int*   partial = cursor + Na;              // P
  int*   esrc    = partial + Pa;             // E
  float* Wc      = (float*)(esrc + Ea);      // 8192
  float* bc      = Wc + 8192;                // 128
  float* pz      = bc + 128;                 // N*64
  float* h1p     = pz + (size_t)N * 64;      // N*128
  float* x1      = h1p + (size_t)N * 128;    // N*128
  float* h2p     = pz;                       // reuse pz (dead after gemm1): N*32
  float* x2      = pz + (size_t)N * 32;      // N*32

  const int nb = (N + 255) / 256;
  const int nw4 = (N + 3) / 4;
  const int poolBlocks = ((N + 3) / 4 < 768) ? (N + 3) / 4 : 768;

  k_zero<<<nb, 256, 0, stream>>>(cnt, N);
  k_count<<<1024, 256, 0, stream>>>(dstp, cnt, E);
  k_scan1<<<P, 256, 0, stream>>>(cnt, rowp, partial, N);
  k_scan2<<<1, 256, 0, stream>>>(partial, P);
  k_scan3<<<P, 256, 0, stream>>>(rowp, partial, cursor, cnt, dinv, N);
  k_edge_fill<<<1024, 256, 0, stream>>>(src, dstp, cursor, esrc, E);
  k_wc<<<33, 256, 0, stream>>>(Wout, bout, W1, Wc, bc);
  k_pool<<<poolBlocks, 256, 0, stream>>>(X, mask, WE, bE, WA, bA, pz, N);
  k_gemm1<<<1024, 256, 0, stream>>>(pz, Wc, bc, dinv, h1p, N);
  k_gather1<<<nw4, 256, 0, stream>>>(rowp, cnt, esrc, h1p, dinv, x1, N);
  k_gemm2<<<1024, 256, 0, stream>>>(x1, b1, W2, dinv, h2p, N);
  k_gather2<<<nw4, 256, 0, stream>>>(rowp, cnt, esrc, h2p, dinv, x2, N);
  k_mlp<<<(B + 255) / 256, 256, 0, stream>>>(qidx, x2, b2, Wm1, bm1, Wm2, bm2, (float*)d_out, B);
}

// Round 12
// 564.445 us; speedup vs baseline: 1.4058x; 1.0134x over previous
//
#include <hip/hip_runtime.h>
#include <math.h>

#define RFL(x) __builtin_amdgcn_readfirstlane(x)
#define RL(x, l) __int_as_float(__builtin_amdgcn_readlane(__float_as_int(x), (l)))

typedef __attribute__((ext_vector_type(8))) short bf16x8;
typedef __attribute__((ext_vector_type(4))) float f32x4;

__device__ inline unsigned short bf16_rne(float f) {
  unsigned u = __float_as_uint(f);
  u += 0x7FFFu + ((u >> 16) & 1u);
  return (unsigned short)(u >> 16);
}

// ---------------- degree histogram (int) ----------------

__global__ __launch_bounds__(256) void k_zero(int* p, int n) {
  int t = blockIdx.x * 256 + threadIdx.x;
  if (t < n) p[t] = 0;
}

__global__ __launch_bounds__(256) void k_count(const int* __restrict__ dst, int* cnt, int E) {
  int stride = gridDim.x * blockDim.x;
  for (int e = blockIdx.x * blockDim.x + threadIdx.x; e < E; e += stride)
    atomicAdd(&cnt[dst[e]], 1);
}

// ---------------- exclusive scan: cnt -> row_start ----------------

__global__ __launch_bounds__(256) void k_scan1(const int* __restrict__ cnt, int* __restrict__ row,
                                               int* __restrict__ partial, int N) {
  __shared__ int sm[256];
  int t = threadIdx.x, g = blockIdx.x * 256 + t;
  int v = (g < N) ? cnt[g] : 0;
  sm[t] = v;
  __syncthreads();
#pragma unroll
  for (int off = 1; off < 256; off <<= 1) {
    int x = 0;
    if (t >= off) x = sm[t - off];
    __syncthreads();
    if (t >= off) sm[t] += x;
    __syncthreads();
  }
  if (g < N) row[g] = sm[t] - v;  // exclusive within block
  if (t == 255) partial[blockIdx.x] = sm[255];
}

__global__ __launch_bounds__(256) void k_scan2(int* __restrict__ partial, int P) {
  __shared__ int sm[256];
  int t = threadIdx.x;
  int carry = 0;
  for (int base = 0; base < P; base += 256) {
    int idx = base + t;
    int v = (idx < P) ? partial[idx] : 0;
    sm[t] = v;
    __syncthreads();
#pragma unroll
    for (int off = 1; off < 256; off <<= 1) {
      int x = 0;
      if (t >= off) x = sm[t - off];
      __syncthreads();
      if (t >= off) sm[t] += x;
      __syncthreads();
    }
    if (idx < P) partial[idx] = carry + sm[t] - v;  // exclusive
    int tot = sm[255];
    __syncthreads();
    carry += tot;
  }
}

// scan3 + dinv fused
__global__ __launch_bounds__(256) void k_scan3(int* __restrict__ row, const int* __restrict__ partial,
                                               int* __restrict__ cursor, const int* __restrict__ cnt,
                                               float* __restrict__ dinv, int N) {
  int g = blockIdx.x * 256 + threadIdx.x;
  if (g < N) {
    int v = row[g] + partial[blockIdx.x];
    row[g] = v;
    cursor[g] = v;
    dinv[g] = rsqrtf((float)cnt[g] + 1.0f);  // +1 self-loop
  }
}

// ---------------- edge placement: dst-sorted src ----------------

__global__ __launch_bounds__(256) void k_edge_fill(const int* __restrict__ src, const int* __restrict__ dst,
                                                   int* __restrict__ cursor, int* __restrict__ esrc, int E) {
  int stride = gridDim.x * blockDim.x;
  for (int e = blockIdx.x * blockDim.x + threadIdx.x; e < E; e += stride) {
    int s = src[e], d = dst[e];
    int pos = atomicAdd(&cursor[d], 1);
    esrc[pos] = s;
  }
}

// ---------------- W_c = W_out @ W1, b_c = b_out @ W1 ----------------

__global__ __launch_bounds__(256) void k_wc(const float* __restrict__ Wout, const float* __restrict__ bout,
                                            const float* __restrict__ W1, float* __restrict__ Wc,
                                            float* __restrict__ bc) {
  int t = blockIdx.x * 256 + threadIdx.x;
  if (t >= 65 * 128) return;
  int h = t >> 7, o = t & 127;
  const float* row = (h < 64) ? (Wout + h * 128) : bout;
  float a = 0.f;
  for (int d = 0; d < 128; ++d) a += row[d] * W1[d * 128 + o];
  if (h < 64) Wc[h * 128 + o] = a;
  else bc[o] = a;
}

// ---------------- attention pooling via MFMA (split-bf16), persistent+pipelined ----------------
// R12 vs R11 (epilogue was ~6us/tile of the 13us/tile critical path):
//  - mask prefetched with next-tile X loads (no exposed HBM latency between barriers)
//  - epilogue 7->5 barriers, 5->3 phases: raw z written to zt right after the MFMA
//    barrier (all threads) while t<80 folds scorep+mask; ONE softmax phase with
//    per-thread duplicated exps (masked rows vanish as exp(-huge)=0, branch-free);
//    weight fused into the pooled sum (wgtA is wave-uniform -> LDS broadcast).

__global__ __launch_bounds__(256, 3) void k_pool(const float* __restrict__ X, const int* __restrict__ mask,
                                                 const float* __restrict__ WE, const float* __restrict__ bE,
                                                 const float* __restrict__ WA, const float* __restrict__ bA,
                                                 float* __restrict__ pz, int N) {
  __shared__ __align__(16) unsigned short Xh[80][136];
  __shared__ __align__(16) unsigned short Xl[80][136];
  __shared__ float scorep[80][4];
  __shared__ float sco[80];
  __shared__ float wgtA[80];
  float* zt = (float*)&Xh[0][0];  // alias: 80*68 f32 = 21760B = sizeof(Xh)

  const int t = threadIdx.x;
  const int lane = t & 63;
  const int wv = t >> 6;     // wave 0..3 = col tile
  const int cb = wv * 16;
  const int l16 = lane & 15;
  const int lg = lane >> 4;  // 0..3

  const long long totRows = (long long)N * 20;
  const int numTiles = (N + 3) / 4;

  // per-thread load coords within a tile
  const int r0 = t >> 5;            // rows r0, r0+8, ..., r0+72
  const int kq4 = (t & 31) * 4;     // float col base

  // ---- B fragments (WE col-tile) in regs, hi/lo: loaded once ----
  bf16x8 bh[4], bl[4];
#pragma unroll
  for (int kk = 0; kk < 4; ++kk) {
    union { bf16x8 v; unsigned short s[8]; } uh, ul;
#pragma unroll
    for (int i = 0; i < 8; ++i) {
      int k = kk * 32 + lg * 8 + i;
      float w = WE[k * 64 + cb + l16];
      unsigned short h = bf16_rne(w);
      uh.s[i] = h;
      ul.s[i] = bf16_rne(w - __uint_as_float((unsigned)h << 16));
    }
    bh[kk] = uh.v;
    bl[kk] = ul.v;
  }
  const float bEv = bE[cb + l16];
  const float WAv = WA[cb + l16];
  const float bAv = bA[0];
  const float NEG = -3.0e38f;

  int tile = blockIdx.x;
  if (tile >= numTiles) return;

  // ---- prefetch first tile: X + mask ----
  float4 xv[10];
#pragma unroll
  for (int q = 0; q < 10; ++q) {
    long long rr = (long long)tile * 80 + r0 + q * 8;
    if (rr >= totRows) rr = totRows - 1;
    xv[q] = *(const float4*)(X + rr * 128 + kq4);
  }
  int mkcur = 1;
  {
    long long mi = (long long)tile * 80 + t;
    if (t < 80) mkcur = (mi < totRows) ? mask[mi] : 0;
  }

  while (true) {
    // ---- convert current tile -> LDS ----
#pragma unroll
    for (int q = 0; q < 10; ++q) {
      const int r = r0 + q * 8;
      const float4 v = xv[q];
      unsigned short h0 = bf16_rne(v.x), h1 = bf16_rne(v.y), h2 = bf16_rne(v.z), h3 = bf16_rne(v.w);
      float f0 = __uint_as_float((unsigned)h0 << 16);
      float f1 = __uint_as_float((unsigned)h1 << 16);
      float f2 = __uint_as_float((unsigned)h2 << 16);
      float f3 = __uint_as_float((unsigned)h3 << 16);
      *(ushort4*)&Xh[r][kq4] = make_ushort4(h0, h1, h2, h3);
      *(ushort4*)&Xl[r][kq4] = make_ushort4(bf16_rne(v.x - f0), bf16_rne(v.y - f1),
                                            bf16_rne(v.z - f2), bf16_rne(v.w - f3));
    }
    __syncthreads();  // staging done

    // ---- issue next tile's loads (X + mask): latency hidden under MFMA+epilogue ----
    const int nextTile = tile + gridDim.x;
    const bool hasNext = nextTile < numTiles;
    float4 xn[10];
    int mknext = 1;
    {
      const long long nb = (long long)(hasNext ? nextTile : tile) * 80;
#pragma unroll
      for (int q = 0; q < 10; ++q) {
        long long rr = nb + r0 + q * 8;
        if (rr >= totRows) rr = totRows - 1;
        xn[q] = *(const float4*)(X + rr * 128 + kq4);
      }
      long long mi = nb + t;
      if (t < 80) mknext = (mi < totRows) ? mask[mi] : 0;
    }

    // ---- MFMA: Z[80][16 cols of this wave] ----
    f32x4 acc[5];
#pragma unroll
    for (int rt = 0; rt < 5; ++rt) acc[rt] = (f32x4){0.f, 0.f, 0.f, 0.f};
#pragma unroll
    for (int rt = 0; rt < 5; ++rt) {
      const int rl = rt * 16 + l16;
#pragma unroll
      for (int kk = 0; kk < 4; ++kk) {
        const int ko = kk * 32 + lg * 8;
        bf16x8 ah = *(const bf16x8*)&Xh[rl][ko];
        bf16x8 al = *(const bf16x8*)&Xl[rl][ko];
        acc[rt] = __builtin_amdgcn_mfma_f32_16x16x32_bf16(ah, bh[kk], acc[rt], 0, 0, 0);
        acc[rt] = __builtin_amdgcn_mfma_f32_16x16x32_bf16(ah, bl[kk], acc[rt], 0, 0, 0);
        acc[rt] = __builtin_amdgcn_mfma_f32_16x16x32_bf16(al, bh[kk], acc[rt], 0, 0, 0);
      }
    }

    // ---- relu + per-row score partials ----
#pragma unroll
    for (int rt = 0; rt < 5; ++rt) {
#pragma unroll
      for (int j = 0; j < 4; ++j) {
        float z = fmaxf(acc[rt][j] + bEv, 0.f);
        acc[rt][j] = z;
        float v = z * WAv;
        v += __shfl_xor(v, 1, 64);
        v += __shfl_xor(v, 2, 64);
        v += __shfl_xor(v, 4, 64);
        v += __shfl_xor(v, 8, 64);
        if (l16 == 0) scorep[rt * 16 + lg * 4 + j][wv] = v;
      }
    }
    __syncthreads();  // barrier 1: MFMA's Xh reads done + scorep visible

    // ---- phase A: all threads dump raw z into zt (aliases Xh); t<80 folds scores ----
#pragma unroll
    for (int rt = 0; rt < 5; ++rt) {
#pragma unroll
      for (int j = 0; j < 4; ++j) {
        int row = rt * 16 + lg * 4 + j;
        zt[row * 68 + cb + l16] = acc[rt][j];
      }
    }
    if (t < 80) {
      float4 sp = *(const float4*)scorep[t];
      float sc = sp.x + sp.y + sp.z + sp.w + bAv;
      if (mkcur == 0) sc = NEG;
      sco[t] = sc;
    }
    __syncthreads();  // barrier 2

    // ---- phase B: single softmax phase (per-thread duplicated exps) ----
    if (t < 80) {
      const int base = (t / 20) * 20;
      float mx = NEG;
#pragma unroll
      for (int i = 0; i < 20; ++i) mx = fmaxf(mx, sco[base + i]);
      float den = 0.f;
#pragma unroll
      for (int i = 0; i < 20; ++i) den += __expf(sco[base + i] - mx);  // masked -> exp(-huge)=0
      wgtA[t] = __expf(sco[t] - mx) / den;
    }
    __syncthreads();  // barrier 3

    // ---- pooled[n][col] = sum_i zt[row_i][col] * wgtA[row_i]; coalesced store ----
    {
      int n = t >> 6, col = t & 63;
      float s = 0.f;
#pragma unroll
      for (int i = 0; i < 20; ++i) s += zt[(n * 20 + i) * 68 + col] * wgtA[n * 20 + i];
      long long node = (long long)tile * 4 + n;
      if (node < N) pz[node * 64 + col] = s;
    }

    if (!hasNext) break;
    __syncthreads();  // barrier 4: zt reads done before next convert writes Xh
#pragma unroll
    for (int q = 0; q < 10; ++q) xv[q] = xn[q];
    mkcur = mknext;
    tile = nextTile;
  }
}

// ---------------- h1p = (pz @ Wc + bc) * dinv[r] ----------------

__global__ __launch_bounds__(256, 2) void k_gemm1(const float* __restrict__ pz, const float* __restrict__ Wc,
                                                  const float* __restrict__ bc, const float* __restrict__ dinv,
                                                  float* __restrict__ h1p, int N) {
  const int lane = threadIdx.x & 63;
  float w0[64], w1[64];
#pragma unroll
  for (int d = 0; d < 64; ++d) {
    w0[d] = Wc[d * 128 + lane];
    w1[d] = Wc[d * 128 + 64 + lane];
  }
  const float b0 = bc[lane], b1v = bc[64 + lane];
  const int nw = (gridDim.x * blockDim.x) >> 6;
  const int w_id = (blockIdx.x * blockDim.x + threadIdx.x) >> 6;
  for (int r = w_id; r < N; r += nw) {
    const float xv = pz[(size_t)r * 64 + lane];
    const int xi = __float_as_int(xv);
    float p0 = 0.f, p1 = 0.f, p2 = 0.f, p3 = 0.f;
#pragma unroll
    for (int d0 = 0; d0 < 64; d0 += 2) {
      float a0 = RL((float&)xi, d0);
      float a1 = RL((float&)xi, d0 + 1);
      p0 += a0 * w0[d0];
      p1 += a0 * w1[d0];
      p2 += a1 * w0[d0 + 1];
      p3 += a1 * w1[d0 + 1];
    }
    float di = dinv[r];
    size_t o = (size_t)r * 128 + lane;
    h1p[o] = (b0 + p0 + p2) * di;
    h1p[o + 64] = (b1v + p1 + p3) * di;
  }
}

// ---------------- gather layer 1 ----------------

__global__ __launch_bounds__(256) void k_gather1(const int* __restrict__ row, const int* __restrict__ cnt,
                                                 const int* __restrict__ esrc, const float* __restrict__ h1p,
                                                 const float* __restrict__ dinv, float* __restrict__ x1, int N) {
  const int lane = threadIdx.x & 63;
  const int node = RFL(blockIdx.x * 4 + (threadIdx.x >> 6));
  if (node >= N) return;
  const int half = lane >> 5, f4 = lane & 31;
  const int rs = RFL(row[node]);
  const int ne = RFL(cnt[node]);
  const float di = dinv[node];
  const float4* __restrict__ hv = (const float4*)h1p;
  float a0 = 0.f, a1 = 0.f, a2 = 0.f, a3 = 0.f;
  int j = half;
  for (; j + 7 <= ne; j += 8) {
    int s0 = esrc[rs + j], s1 = esrc[rs + j + 2], s2 = esrc[rs + j + 4], s3 = esrc[rs + j + 6];
    float4 v0 = hv[(size_t)s0 * 32 + f4];
    float4 v1 = hv[(size_t)s1 * 32 + f4];
    float4 v2 = hv[(size_t)s2 * 32 + f4];
    float4 v3 = hv[(size_t)s3 * 32 + f4];
    a0 += v0.x + v1.x + v2.x + v3.x;
    a1 += v0.y + v1.y + v2.y + v3.y;
    a2 += v0.z + v1.z + v2.z + v3.z;
    a3 += v0.w + v1.w + v2.w + v3.w;
  }
  for (; j < ne; j += 2) {
    int s = esrc[rs + j];
    float4 v = hv[(size_t)s * 32 + f4];
    a0 += v.x; a1 += v.y; a2 += v.z; a3 += v.w;
  }
  a0 += __shfl_xor(a0, 32, 64);
  a1 += __shfl_xor(a1, 32, 64);
  a2 += __shfl_xor(a2, 32, 64);
  a3 += __shfl_xor(a3, 32, 64);
  if (half == 0) {
    float4 sv = hv[(size_t)node * 32 + f4];
    float4 o;
    o.x = (a0 + sv.x * di) * di;
    o.y = (a1 + sv.y * di) * di;
    o.z = (a2 + sv.z * di) * di;
    o.w = (a3 + sv.w * di) * di;
    ((float4*)x1)[(size_t)node * 32 + f4] = o;
  }
}

// ---------------- h2p = (relu(x1 + b1) @ W2) * dinv[r] ----------------

__global__ __launch_bounds__(256, 2) void k_gemm2(const float* __restrict__ x1, const float* __restrict__ b1,
                                                  const float* __restrict__ W2, const float* __restrict__ dinv,
                                                  float* __restrict__ h2p, int N) {
  const int lane = threadIdx.x & 63;
  const int col = lane & 31;
  float w[128];
#pragma unroll
  for (int d = 0; d < 128; ++d) w[d] = W2[d * 32 + col];
  const float bb0 = b1[lane], bb1 = b1[64 + lane];
  const int nw = (gridDim.x * blockDim.x) >> 6;
  const int w_id = (blockIdx.x * blockDim.x + threadIdx.x) >> 6;
  for (int r = w_id; r < N; r += nw) {
    float rx0 = fmaxf(x1[(size_t)r * 128 + lane] + bb0, 0.f);
    float rx1 = fmaxf(x1[(size_t)r * 128 + 64 + lane] + bb1, 0.f);
    const int xi0 = __float_as_int(rx0), xi1 = __float_as_int(rx1);
    float p0 = 0.f, p1 = 0.f, p2 = 0.f, p3 = 0.f;
#pragma unroll
    for (int d0 = 0; d0 < 64; d0 += 2) {
      float a0 = RL((float&)xi0, d0);
      float a1 = RL((float&)xi0, d0 + 1);
      float c0 = RL((float&)xi1, d0);
      float c1 = RL((float&)xi1, d0 + 1);
      p0 += a0 * w[d0];
      p1 += a1 * w[d0 + 1];
      p2 += c0 * w[64 + d0];
      p3 += c1 * w[64 + d0 + 1];
    }
    if (lane < 32) {
      float di = dinv[r];
      h2p[(size_t)r * 32 + col] = ((p0 + p1) + (p2 + p3)) * di;
    }
  }
}

// ---------------- gather layer 2 ----------------

__global__ __launch_bounds__(256) void k_gather2(const int* __restrict__ row, const int* __restrict__ cnt,
                                                 const int* __restrict__ esrc, const float* __restrict__ h2p,
                                                 const float* __restrict__ dinv, float* __restrict__ x2, int N) {
  const int lane = threadIdx.x & 63;
  const int node = RFL(blockIdx.x * 4 + (threadIdx.x >> 6));
  if (node >= N) return;
  const int q = lane >> 3, f4 = lane & 7;
  const int rs = RFL(row[node]);
  const int ne = RFL(cnt[node]);
  const float di = dinv[node];
  const float4* __restrict__ hv = (const float4*)h2p;
  float a0 = 0.f, a1 = 0.f, a2 = 0.f, a3 = 0.f;
  int j = q;
  for (; j + 9 <= ne; j += 16) {
    int s0 = esrc[rs + j], s1 = esrc[rs + j + 8];
    float4 v0 = hv[(size_t)s0 * 8 + f4];
    float4 v1 = hv[(size_t)s1 * 8 + f4];
    a0 += v0.x + v1.x;
    a1 += v0.y + v1.y;
    a2 += v0.z + v1.z;
    a3 += v0.w + v1.w;
  }
  for (; j < ne; j += 8) {
    int s = esrc[rs + j];
    float4 v = hv[(size_t)s * 8 + f4];
    a0 += v.x; a1 += v.y; a2 += v.z; a3 += v.w;
  }
#pragma unroll
  for (int off = 8; off <= 32; off <<= 1) {
    a0 += __shfl_xor(a0, off, 64);
    a1 += __shfl_xor(a1, off, 64);
    a2 += __shfl_xor(a2, off, 64);
    a3 += __shfl_xor(a3, off, 64);
  }
  if (q == 0) {
    float4 sv = hv[(size_t)node * 8 + f4];
    float4 o;
    o.x = (a0 + sv.x * di) * di;
    o.y = (a1 + sv.y * di) * di;
    o.z = (a2 + sv.z * di) * di;
    o.w = (a3 + sv.w * di) * di;
    ((float4*)x2)[(size_t)node * 8 + f4] = o;
  }
}

// ---------------- query MLP ----------------

__global__ __launch_bounds__(256) void k_mlp(const int* __restrict__ qidx, const float* __restrict__ x2,
                                             const float* __restrict__ b2, const float* __restrict__ Wm1,
                                             const float* __restrict__ bm1, const float* __restrict__ Wm2,
                                             const float* __restrict__ bm2, float* __restrict__ out, int B) {
  int t = blockIdx.x * 256 + threadIdx.x;
  if (t >= B) return;
  int n = qidx[t];
  float qv[32];
#pragma unroll
  for (int k = 0; k < 32; ++k) qv[k] = fmaxf(x2[(size_t)n * 32 + k] + b2[k], 0.f);
  float acc = bm2[0];
  for (int j = 0; j < 64; ++j) {
    float h = bm1[j];
#pragma unroll
    for (int k = 0; k < 32; ++k) h += qv[k] * Wm1[k * 64 + j];
    acc += fmaxf(h, 0.f) * Wm2[j];
  }
  out[t] = acc;
}

// ---------------- launcher ----------------

extern "C" void kernel_launch(void* const* d_in, const int* in_sizes, int n_in,
                              void* d_out, int out_size, void* d_ws, size_t ws_size,
                              hipStream_t stream) {
  const float* X    = (const float*)d_in[0];
  const int*   mask = (const int*)d_in[1];
  const int*   ei   = (const int*)d_in[2];
  const int*   qidx = (const int*)d_in[3];
  const float* WE   = (const float*)d_in[4];
  const float* bE   = (const float*)d_in[5];
  const float* WA   = (const float*)d_in[6];
  const float* bA   = (const float*)d_in[7];
  const float* Wout = (const float*)d_in[8];
  const float* bout = (const float*)d_in[9];
  const float* W1   = (const float*)d_in[10];
  const float* b1   = (const float*)d_in[11];
  const float* W2   = (const float*)d_in[12];
  const float* b2   = (const float*)d_in[13];
  const float* Wm1  = (const float*)d_in[14];
  const float* bm1  = (const float*)d_in[15];
  const float* Wm2  = (const float*)d_in[16];
  const float* bm2  = (const float*)d_in[17];

  const int N = in_sizes[1] / 20;
  const int E = in_sizes[2] / 2;
  const int B = in_sizes[3];
  const int* src  = ei;
  const int* dstp = ei + E;

  const size_t Na = ((size_t)N + 63) & ~(size_t)63;
  const size_t Ea = ((size_t)E + 63) & ~(size_t)63;
  const int P = (N + 255) / 256;
  const size_t Pa = ((size_t)P + 63) & ~(size_t)63;

  float* ws      = (float*)d_ws;
  float* dinv    = ws;                       // N
  int*   cnt     = (int*)(dinv + Na);        // N
  int*   rowp    = cnt + Na;                 // N
  int*   cursor  = rowp + Na;                // N
  int*   partial = cursor + Na;              // P
  int*   esrc    = partial + Pa;             // E
  float* Wc      = (float*)(esrc + Ea);      // 8192
  float* bc      = Wc + 8192;                // 128
  float* pz      = bc + 128;                 // N*64
  float* h1p     = pz + (size_t)N * 64;      // N*128
  float* x1      = h1p + (size_t)N * 128;    // N*128
  float* h2p     = pz;                       // reuse pz (dead after gemm1): N*32
  float* x2      = pz + (size_t)N * 32;      // N*32

  const int nb = (N + 255) / 256;
  const int nw4 = (N + 3) / 4;
  const int poolBlocks = ((N + 3) / 4 < 768) ? (N + 3) / 4 : 768;

  k_zero<<<nb, 256, 0, stream>>>(cnt, N);
  k_count<<<1024, 256, 0, stream>>>(dstp, cnt, E);
  k_scan1<<<P, 256, 0, stream>>>(cnt, rowp, partial, N);
  k_scan2<<<1, 256, 0, stream>>>(partial, P);
  k_scan3<<<P, 256, 0, stream>>>(rowp, partial, cursor, cnt, dinv, N);
  k_edge_fill<<<1024, 256, 0, stream>>>(src, dstp, cursor, esrc, E);
  k_wc<<<33, 256, 0, stream>>>(Wout, bout, W1, Wc, bc);
  k_pool<<<poolBlocks, 256, 0, stream>>>(X, mask, WE, bE, WA, bA, pz, N);
  k_gemm1<<<1024, 256, 0, stream>>>(pz, Wc, bc, dinv, h1p, N);
  k_gather1<<<nw4, 256, 0, stream>>>(rowp, cnt, esrc, h1p, dinv, x1, N);
  k_gemm2<<<1024, 256, 0, stream>>>(x1, b1, W2, dinv, h2p, N);
  k_gather2<<<nw4, 256, 0, stream>>>(rowp, cnt, esrc, h2p, dinv, x2, N);
  k_mlp<<<(B + 255) / 256, 256, 0, stream>>>(qidx, x2, b2, Wm1, bm1, Wm2, bm2, (float*)d_out, B);
}

// Round 13
// 564.168 us; speedup vs baseline: 1.4065x; 1.0005x over previous
//
#include <hip/hip_runtime.h>
#include <math.h>

#define RFL(x) __builtin_amdgcn_readfirstlane(x)
#define RL(x, l) __int_as_float(__builtin_amdgcn_readlane(__float_as_int(x), (l)))

typedef __attribute__((ext_vector_type(8))) short bf16x8;
typedef __attribute__((ext_vector_type(4))) float f32x4;

__device__ inline unsigned short bf16_rne(float f) {
  unsigned u = __float_as_uint(f);
  u += 0x7FFFu + ((u >> 16) & 1u);
  return (unsigned short)(u >> 16);
}

// ---------------- degree histogram (int) ----------------

__global__ __launch_bounds__(256) void k_zero(int* p, int n) {
  int t = blockIdx.x * 256 + threadIdx.x;
  if (t < n) p[t] = 0;
}

__global__ __launch_bounds__(256) void k_count(const int* __restrict__ dst, int* cnt, int E) {
  int stride = gridDim.x * blockDim.x;
  for (int e = blockIdx.x * blockDim.x + threadIdx.x; e < E; e += stride)
    atomicAdd(&cnt[dst[e]], 1);
}

// ---------------- exclusive scan: cnt -> row_start ----------------

__global__ __launch_bounds__(256) void k_scan1(const int* __restrict__ cnt, int* __restrict__ row,
                                               int* __restrict__ partial, int N) {
  __shared__ int sm[256];
  int t = threadIdx.x, g = blockIdx.x * 256 + t;
  int v = (g < N) ? cnt[g] : 0;
  sm[t] = v;
  __syncthreads();
#pragma unroll
  for (int off = 1; off < 256; off <<= 1) {
    int x = 0;
    if (t >= off) x = sm[t - off];
    __syncthreads();
    if (t >= off) sm[t] += x;
    __syncthreads();
  }
  if (g < N) row[g] = sm[t] - v;  // exclusive within block
  if (t == 255) partial[blockIdx.x] = sm[255];
}

__global__ __launch_bounds__(256) void k_scan2(int* __restrict__ partial, int P) {
  __shared__ int sm[256];
  int t = threadIdx.x;
  int carry = 0;
  for (int base = 0; base < P; base += 256) {
    int idx = base + t;
    int v = (idx < P) ? partial[idx] : 0;
    sm[t] = v;
    __syncthreads();
#pragma unroll
    for (int off = 1; off < 256; off <<= 1) {
      int x = 0;
      if (t >= off) x = sm[t - off];
      __syncthreads();
      if (t >= off) sm[t] += x;
      __syncthreads();
    }
    if (idx < P) partial[idx] = carry + sm[t] - v;  // exclusive
    int tot = sm[255];
    __syncthreads();
    carry += tot;
  }
}

// scan3 + dinv fused
__global__ __launch_bounds__(256) void k_scan3(int* __restrict__ row, const int* __restrict__ partial,
                                               int* __restrict__ cursor, const int* __restrict__ cnt,
                                               float* __restrict__ dinv, int N) {
  int g = blockIdx.x * 256 + threadIdx.x;
  if (g < N) {
    int v = row[g] + partial[blockIdx.x];
    row[g] = v;
    cursor[g] = v;
    dinv[g] = rsqrtf((float)cnt[g] + 1.0f);  // +1 self-loop
  }
}

// ---------------- edge placement: dst-sorted src ----------------

__global__ __launch_bounds__(256) void k_edge_fill(const int* __restrict__ src, const int* __restrict__ dst,
                                                   int* __restrict__ cursor, int* __restrict__ esrc, int E) {
  int stride = gridDim.x * blockDim.x;
  for (int e = blockIdx.x * blockDim.x + threadIdx.x; e < E; e += stride) {
    int s = src[e], d = dst[e];
    int pos = atomicAdd(&cursor[d], 1);
    esrc[pos] = s;
  }
}

// ---------------- W_c = W_out @ W1, b_c = b_out @ W1 ----------------

__global__ __launch_bounds__(256) void k_wc(const float* __restrict__ Wout, const float* __restrict__ bout,
                                            const float* __restrict__ W1, float* __restrict__ Wc,
                                            float* __restrict__ bc) {
  int t = blockIdx.x * 256 + threadIdx.x;
  if (t >= 65 * 128) return;
  int h = t >> 7, o = t & 127;
  const float* row = (h < 64) ? (Wout + h * 128) : bout;
  float a = 0.f;
  for (int d = 0; d < 128; ++d) a += row[d] * W1[d * 128 + o];
  if (h < 64) Wc[h * 128 + o] = a;
  else bc[o] = a;
}

// ---------------- attention pooling via MFMA (split-bf16), persistent+pipelined ----------------
// (unchanged from R12)

__global__ __launch_bounds__(256, 3) void k_pool(const float* __restrict__ X, const int* __restrict__ mask,
                                                 const float* __restrict__ WE, const float* __restrict__ bE,
                                                 const float* __restrict__ WA, const float* __restrict__ bA,
                                                 float* __restrict__ pz, int N) {
  __shared__ __align__(16) unsigned short Xh[80][136];
  __shared__ __align__(16) unsigned short Xl[80][136];
  __shared__ float scorep[80][4];
  __shared__ float sco[80];
  __shared__ float wgtA[80];
  float* zt = (float*)&Xh[0][0];  // alias: 80*68 f32 = 21760B = sizeof(Xh)

  const int t = threadIdx.x;
  const int lane = t & 63;
  const int wv = t >> 6;     // wave 0..3 = col tile
  const int cb = wv * 16;
  const int l16 = lane & 15;
  const int lg = lane >> 4;  // 0..3

  const long long totRows = (long long)N * 20;
  const int numTiles = (N + 3) / 4;

  const int r0 = t >> 5;            // rows r0, r0+8, ..., r0+72
  const int kq4 = (t & 31) * 4;     // float col base

  bf16x8 bh[4], bl[4];
#pragma unroll
  for (int kk = 0; kk < 4; ++kk) {
    union { bf16x8 v; unsigned short s[8]; } uh, ul;
#pragma unroll
    for (int i = 0; i < 8; ++i) {
      int k = kk * 32 + lg * 8 + i;
      float w = WE[k * 64 + cb + l16];
      unsigned short h = bf16_rne(w);
      uh.s[i] = h;
      ul.s[i] = bf16_rne(w - __uint_as_float((unsigned)h << 16));
    }
    bh[kk] = uh.v;
    bl[kk] = ul.v;
  }
  const float bEv = bE[cb + l16];
  const float WAv = WA[cb + l16];
  const float bAv = bA[0];
  const float NEG = -3.0e38f;

  int tile = blockIdx.x;
  if (tile >= numTiles) return;

  float4 xv[10];
#pragma unroll
  for (int q = 0; q < 10; ++q) {
    long long rr = (long long)tile * 80 + r0 + q * 8;
    if (rr >= totRows) rr = totRows - 1;
    xv[q] = *(const float4*)(X + rr * 128 + kq4);
  }
  int mkcur = 1;
  {
    long long mi = (long long)tile * 80 + t;
    if (t < 80) mkcur = (mi < totRows) ? mask[mi] : 0;
  }

  while (true) {
#pragma unroll
    for (int q = 0; q < 10; ++q) {
      const int r = r0 + q * 8;
      const float4 v = xv[q];
      unsigned short h0 = bf16_rne(v.x), h1 = bf16_rne(v.y), h2 = bf16_rne(v.z), h3 = bf16_rne(v.w);
      float f0 = __uint_as_float((unsigned)h0 << 16);
      float f1 = __uint_as_float((unsigned)h1 << 16);
      float f2 = __uint_as_float((unsigned)h2 << 16);
      float f3 = __uint_as_float((unsigned)h3 << 16);
      *(ushort4*)&Xh[r][kq4] = make_ushort4(h0, h1, h2, h3);
      *(ushort4*)&Xl[r][kq4] = make_ushort4(bf16_rne(v.x - f0), bf16_rne(v.y - f1),
                                            bf16_rne(v.z - f2), bf16_rne(v.w - f3));
    }
    __syncthreads();  // staging done

    const int nextTile = tile + gridDim.x;
    const bool hasNext = nextTile < numTiles;
    float4 xn[10];
    int mknext = 1;
    {
      const long long nb = (long long)(hasNext ? nextTile : tile) * 80;
#pragma unroll
      for (int q = 0; q < 10; ++q) {
        long long rr = nb + r0 + q * 8;
        if (rr >= totRows) rr = totRows - 1;
        xn[q] = *(const float4*)(X + rr * 128 + kq4);
      }
      long long mi = nb + t;
      if (t < 80) mknext = (mi < totRows) ? mask[mi] : 0;
    }

    f32x4 acc[5];
#pragma unroll
    for (int rt = 0; rt < 5; ++rt) acc[rt] = (f32x4){0.f, 0.f, 0.f, 0.f};
#pragma unroll
    for (int rt = 0; rt < 5; ++rt) {
      const int rl = rt * 16 + l16;
#pragma unroll
      for (int kk = 0; kk < 4; ++kk) {
        const int ko = kk * 32 + lg * 8;
        bf16x8 ah = *(const bf16x8*)&Xh[rl][ko];
        bf16x8 al = *(const bf16x8*)&Xl[rl][ko];
        acc[rt] = __builtin_amdgcn_mfma_f32_16x16x32_bf16(ah, bh[kk], acc[rt], 0, 0, 0);
        acc[rt] = __builtin_amdgcn_mfma_f32_16x16x32_bf16(ah, bl[kk], acc[rt], 0, 0, 0);
        acc[rt] = __builtin_amdgcn_mfma_f32_16x16x32_bf16(al, bh[kk], acc[rt], 0, 0, 0);
      }
    }

#pragma unroll
    for (int rt = 0; rt < 5; ++rt) {
#pragma unroll
      for (int j = 0; j < 4; ++j) {
        float z = fmaxf(acc[rt][j] + bEv, 0.f);
        acc[rt][j] = z;
        float v = z * WAv;
        v += __shfl_xor(v, 1, 64);
        v += __shfl_xor(v, 2, 64);
        v += __shfl_xor(v, 4, 64);
        v += __shfl_xor(v, 8, 64);
        if (l16 == 0) scorep[rt * 16 + lg * 4 + j][wv] = v;
      }
    }
    __syncthreads();  // barrier 1

#pragma unroll
    for (int rt = 0; rt < 5; ++rt) {
#pragma unroll
      for (int j = 0; j < 4; ++j) {
        int row = rt * 16 + lg * 4 + j;
        zt[row * 68 + cb + l16] = acc[rt][j];
      }
    }
    if (t < 80) {
      float4 sp = *(const float4*)scorep[t];
      float sc = sp.x + sp.y + sp.z + sp.w + bAv;
      if (mkcur == 0) sc = NEG;
      sco[t] = sc;
    }
    __syncthreads();  // barrier 2

    if (t < 80) {
      const int base = (t / 20) * 20;
      float mx = NEG;
#pragma unroll
      for (int i = 0; i < 20; ++i) mx = fmaxf(mx, sco[base + i]);
      float den = 0.f;
#pragma unroll
      for (int i = 0; i < 20; ++i) den += __expf(sco[base + i] - mx);
      wgtA[t] = __expf(sco[t] - mx) / den;
    }
    __syncthreads();  // barrier 3

    {
      int n = t >> 6, col = t & 63;
      float s = 0.f;
#pragma unroll
      for (int i = 0; i < 20; ++i) s += zt[(n * 20 + i) * 68 + col] * wgtA[n * 20 + i];
      long long node = (long long)tile * 4 + n;
      if (node < N) pz[node * 64 + col] = s;
    }

    if (!hasNext) break;
    __syncthreads();  // barrier 4
#pragma unroll
    for (int q = 0; q < 10; ++q) xv[q] = xn[q];
    mkcur = mknext;
    tile = nextTile;
  }
}

// ---------------- h1p = (pz @ Wc + bc) * dinv[r] ----------------

__global__ __launch_bounds__(256, 2) void k_gemm1(const float* __restrict__ pz, const float* __restrict__ Wc,
                                                  const float* __restrict__ bc, const float* __restrict__ dinv,
                                                  float* __restrict__ h1p, int N) {
  const int lane = threadIdx.x & 63;
  float w0[64], w1[64];
#pragma unroll
  for (int d = 0; d < 64; ++d) {
    w0[d] = Wc[d * 128 + lane];
    w1[d] = Wc[d * 128 + 64 + lane];
  }
  const float b0 = bc[lane], b1v = bc[64 + lane];
  const int nw = (gridDim.x * blockDim.x) >> 6;
  const int w_id = (blockIdx.x * blockDim.x + threadIdx.x) >> 6;
  for (int r = w_id; r < N; r += nw) {
    const float xv = pz[(size_t)r * 64 + lane];
    const int xi = __float_as_int(xv);
    float p0 = 0.f, p1 = 0.f, p2 = 0.f, p3 = 0.f;
#pragma unroll
    for (int d0 = 0; d0 < 64; d0 += 2) {
      float a0 = RL((float&)xi, d0);
      float a1 = RL((float&)xi, d0 + 1);
      p0 += a0 * w0[d0];
      p1 += a0 * w1[d0];
      p2 += a1 * w0[d0 + 1];
      p3 += a1 * w1[d0 + 1];
    }
    float di = dinv[r];
    size_t o = (size_t)r * 128 + lane;
    h1p[o] = (b0 + p0 + p2) * di;
    h1p[o + 64] = (b1v + p1 + p3) * di;
  }
}

// ---------------- gather layer 1: x1[d] = dinv[d]*(sum_in h1p[s] + h1p[d]*dinv[d]) ----------------
// R13: 16-edge chunks; half h owns a CONTIGUOUS 8-edge run -> 16 float4 gathers
// in flight per wave, contiguous esrc reads. Final partial chunk runs at the
// SAME depth with clamped indices + 0/1 mask (no 1-deep tail).

__global__ __launch_bounds__(256) void k_gather1(const int* __restrict__ row, const int* __restrict__ cnt,
                                                 const int* __restrict__ esrc, const float* __restrict__ h1p,
                                                 const float* __restrict__ dinv, float* __restrict__ x1, int N) {
  const int lane = threadIdx.x & 63;
  const int node = RFL(blockIdx.x * 4 + (threadIdx.x >> 6));
  if (node >= N) return;
  const int half = lane >> 5, f4 = lane & 31;
  const int rs = RFL(row[node]);
  const int ne = RFL(cnt[node]);
  const float di = dinv[node];
  const float4* __restrict__ hv = (const float4*)h1p;
  float a0 = 0.f, a1 = 0.f, a2 = 0.f, a3 = 0.f;
  int j = 0;
  for (; j + 16 <= ne; j += 16) {  // full chunk: half owns edges [j+8*half, j+8*half+8)
    const int b = rs + j + half * 8;
    int s[8];
#pragma unroll
    for (int u = 0; u < 8; ++u) s[u] = esrc[b + u];
    float4 v[8];
#pragma unroll
    for (int u = 0; u < 8; ++u) v[u] = hv[(size_t)s[u] * 32 + f4];
#pragma unroll
    for (int u = 0; u < 8; ++u) {
      a0 += v[u].x; a1 += v[u].y; a2 += v[u].z; a3 += v[u].w;
    }
  }
  if (j < ne) {  // partial chunk, same depth, masked
    const int b = j + half * 8;
    int s[8];
    float m[8];
#pragma unroll
    for (int u = 0; u < 8; ++u) {
      int idx = b + u;
      int c = (idx < ne) ? idx : (ne - 1);
      s[u] = esrc[rs + c];
      m[u] = (idx < ne) ? 1.f : 0.f;
    }
    float4 v[8];
#pragma unroll
    for (int u = 0; u < 8; ++u) v[u] = hv[(size_t)s[u] * 32 + f4];
#pragma unroll
    for (int u = 0; u < 8; ++u) {
      a0 += v[u].x * m[u]; a1 += v[u].y * m[u]; a2 += v[u].z * m[u]; a3 += v[u].w * m[u];
    }
  }
  a0 += __shfl_xor(a0, 32, 64);
  a1 += __shfl_xor(a1, 32, 64);
  a2 += __shfl_xor(a2, 32, 64);
  a3 += __shfl_xor(a3, 32, 64);
  if (half == 0) {
    float4 sv = hv[(size_t)node * 32 + f4];
    float4 o;
    o.x = (a0 + sv.x * di) * di;
    o.y = (a1 + sv.y * di) * di;
    o.z = (a2 + sv.z * di) * di;
    o.w = (a3 + sv.w * di) * di;
    ((float4*)x1)[(size_t)node * 32 + f4] = o;
  }
}

// ---------------- h2p = (relu(x1 + b1) @ W2) * dinv[r] ----------------

__global__ __launch_bounds__(256, 2) void k_gemm2(const float* __restrict__ x1, const float* __restrict__ b1,
                                                  const float* __restrict__ W2, const float* __restrict__ dinv,
                                                  float* __restrict__ h2p, int N) {
  const int lane = threadIdx.x & 63;
  const int col = lane & 31;
  float w[128];
#pragma unroll
  for (int d = 0; d < 128; ++d) w[d] = W2[d * 32 + col];
  const float bb0 = b1[lane], bb1 = b1[64 + lane];
  const int nw = (gridDim.x * blockDim.x) >> 6;
  const int w_id = (blockIdx.x * blockDim.x + threadIdx.x) >> 6;
  for (int r = w_id; r < N; r += nw) {
    float rx0 = fmaxf(x1[(size_t)r * 128 + lane] + bb0, 0.f);
    float rx1 = fmaxf(x1[(size_t)r * 128 + 64 + lane] + bb1, 0.f);
    const int xi0 = __float_as_int(rx0), xi1 = __float_as_int(rx1);
    float p0 = 0.f, p1 = 0.f, p2 = 0.f, p3 = 0.f;
#pragma unroll
    for (int d0 = 0; d0 < 64; d0 += 2) {
      float a0 = RL((float&)xi0, d0);
      float a1 = RL((float&)xi0, d0 + 1);
      float c0 = RL((float&)xi1, d0);
      float c1 = RL((float&)xi1, d0 + 1);
      p0 += a0 * w[d0];
      p1 += a1 * w[d0 + 1];
      p2 += c0 * w[64 + d0];
      p3 += c1 * w[64 + d0 + 1];
    }
    if (lane < 32) {
      float di = dinv[r];
      h2p[(size_t)r * 32 + col] = ((p0 + p1) + (p2 + p3)) * di;
    }
  }
}

// ---------------- gather layer 2: 32-edge chunks; group q owns 4 contiguous edges ----------------
// 32 float4 gathers in flight per wave; masked final chunk (no 1-deep tail).

__global__ __launch_bounds__(256) void k_gather2(const int* __restrict__ row, const int* __restrict__ cnt,
                                                 const int* __restrict__ esrc, const float* __restrict__ h2p,
                                                 const float* __restrict__ dinv, float* __restrict__ x2, int N) {
  const int lane = threadIdx.x & 63;
  const int node = RFL(blockIdx.x * 4 + (threadIdx.x >> 6));
  if (node >= N) return;
  const int q = lane >> 3, f4 = lane & 7;  // group 0..7, float4 slot 0..7 (8x4=32 floats)
  const int rs = RFL(row[node]);
  const int ne = RFL(cnt[node]);
  const float di = dinv[node];
  const float4* __restrict__ hv = (const float4*)h2p;
  float a0 = 0.f, a1 = 0.f, a2 = 0.f, a3 = 0.f;
  int j = 0;
  for (; j + 32 <= ne; j += 32) {  // full chunk: group owns [j+4q, j+4q+4)
    const int b = rs + j + q * 4;
    int s[4];
#pragma unroll
    for (int u = 0; u < 4; ++u) s[u] = esrc[b + u];
    float4 v[4];
#pragma unroll
    for (int u = 0; u < 4; ++u) v[u] = hv[(size_t)s[u] * 8 + f4];
#pragma unroll
    for (int u = 0; u < 4; ++u) {
      a0 += v[u].x; a1 += v[u].y; a2 += v[u].z; a3 += v[u].w;
    }
  }
  if (j < ne) {  // partial chunk, masked
    const int b = j + q * 4;
    int s[4];
    float m[4];
#pragma unroll
    for (int u = 0; u < 4; ++u) {
      int idx = b + u;
      int c = (idx < ne) ? idx : (ne - 1);
      s[u] = esrc[rs + c];
      m[u] = (idx < ne) ? 1.f : 0.f;
    }
    float4 v[4];
#pragma unroll
    for (int u = 0; u < 4; ++u) v[u] = hv[(size_t)s[u] * 8 + f4];
#pragma unroll
    for (int u = 0; u < 4; ++u) {
      a0 += v[u].x * m[u]; a1 += v[u].y * m[u]; a2 += v[u].z * m[u]; a3 += v[u].w * m[u];
    }
  }
#pragma unroll
  for (int off = 8; off <= 32; off <<= 1) {
    a0 += __shfl_xor(a0, off, 64);
    a1 += __shfl_xor(a1, off, 64);
    a2 += __shfl_xor(a2, off, 64);
    a3 += __shfl_xor(a3, off, 64);
  }
  if (q == 0) {
    float4 sv = hv[(size_t)node * 8 + f4];
    float4 o;
    o.x = (a0 + sv.x * di) * di;
    o.y = (a1 + sv.y * di) * di;
    o.z = (a2 + sv.z * di) * di;
    o.w = (a3 + sv.w * di) * di;
    ((float4*)x2)[(size_t)node * 8 + f4] = o;
  }
}

// ---------------- query MLP ----------------

__global__ __launch_bounds__(256) void k_mlp(const int* __restrict__ qidx, const float* __restrict__ x2,
                                             const float* __restrict__ b2, const float* __restrict__ Wm1,
                                             const float* __restrict__ bm1, const float* __restrict__ Wm2,
                                             const float* __restrict__ bm2, float* __restrict__ out, int B) {
  int t = blockIdx.x * 256 + threadIdx.x;
  if (t >= B) return;
  int n = qidx[t];
  float qv[32];
#pragma unroll
  for (int k = 0; k < 32; ++k) qv[k] = fmaxf(x2[(size_t)n * 32 + k] + b2[k], 0.f);
  float acc = bm2[0];
  for (int j = 0; j < 64; ++j) {
    float h = bm1[j];
#pragma unroll
    for (int k = 0; k < 32; ++k) h += qv[k] * Wm1[k * 64 + j];
    acc += fmaxf(h, 0.f) * Wm2[j];
  }
  out[t] = acc;
}

// ---------------- launcher ----------------

extern "C" void kernel_launch(void* const* d_in, const int* in_sizes, int n_in,
                              void* d_out, int out_size, void* d_ws, size_t ws_size,
                              hipStream_t stream) {
  const float* X    = (const float*)d_in[0];
  const int*   mask = (const int*)d_in[1];
  const int*   ei   = (const int*)d_in[2];
  const int*   qidx = (const int*)d_in[3];
  const float* WE   = (const float*)d_in[4];
  const float* bE   = (const float*)d_in[5];
  const float* WA   = (const float*)d_in[6];
  const float* bA   = (const float*)d_in[7];
  const float* Wout = (const float*)d_in[8];
  const float* bout = (const float*)d_in[9];
  const float* W1   = (const float*)d_in[10];
  const float* b1   = (const float*)d_in[11];
  const float* W2   = (const float*)d_in[12];
  const float* b2   = (const float*)d_in[13];
  const float* Wm1  = (const float*)d_in[14];
  const float* bm1  = (const float*)d_in[15];
  const float* Wm2  = (const float*)d_in[16];
  const float* bm2  = (const float*)d_in[17];

  const int N = in_sizes[1] / 20;
  const int E = in_sizes[2] / 2;
  const int B = in_sizes[3];
  const int* src  = ei;
  const int* dstp = ei + E;

  const size_t Na = ((size_t)N + 63) & ~(size_t)63;
  const size_t Ea = ((size_t)E + 63) & ~(size_t)63;
  const int P = (N + 255) / 256;
  const size_t Pa = ((size_t)P + 63) & ~(size_t)63;

  float* ws      = (float*)d_ws;
  float* dinv    = ws;                       // N
  int*   cnt     = (int*)(dinv + Na);        // N
  int*   rowp    = cnt + Na;                 // N
  int*   cursor  = rowp + Na;                // N
  int*   partial = cursor + Na;              // P
  int*   esrc    = partial + Pa;             // E
  float* Wc      = (float*)(esrc + Ea);      // 8192
  float* bc      = Wc + 8192;                // 128
  float* pz      = bc + 128;                 // N*64
  float* h1p     = pz + (size_t)N * 64;      // N*128
  float* x1      = h1p + (size_t)N * 128;    // N*128
  float* h2p     = pz;                       // reuse pz (dead after gemm1): N*32
  float* x2      = pz + (size_t)N * 32;      // N*32

  const int nb = (N + 255) / 256;
  const int nw4 = (N + 3) / 4;
  const int poolBlocks = ((N + 3) / 4 < 768) ? (N + 3) / 4 : 768;

  k_zero<<<nb, 256, 0, stream>>>(cnt, N);
  k_count<<<1024, 256, 0, stream>>>(dstp, cnt, E);
  k_scan1<<<P, 256, 0, stream>>>(cnt, rowp, partial, N);
  k_scan2<<<1, 256, 0, stream>>>(partial, P);
  k_scan3<<<P, 256, 0, stream>>>(rowp, partial, cursor, cnt, dinv, N);
  k_edge_fill<<<1024, 256, 0, stream>>>(src, dstp, cursor, esrc, E);
  k_wc<<<33, 256, 0, stream>>>(Wout, bout, W1, Wc, bc);
  k_pool<<<poolBlocks, 256, 0, stream>>>(X, mask, WE, bE, WA, bA, pz, N);
  k_gemm1<<<1024, 256, 0, stream>>>(pz, Wc, bc, dinv, h1p, N);
  k_gather1<<<nw4, 256, 0, stream>>>(rowp, cnt, esrc, h1p, dinv, x1, N);
  k_gemm2<<<1024, 256, 0, stream>>>(x1, b1, W2, dinv, h2p, N);
  k_gather2<<<nw4, 256, 0, stream>>>(rowp, cnt, esrc, h2p, dinv, x2, N);
  k_mlp<<<(B + 255) / 256, 256, 0, stream>>>(qidx, x2, b2, Wm1, bm1, Wm2, bm2, (float*)d_out, B);
}

// Round 14
// 510.459 us; speedup vs baseline: 1.5545x; 1.1052x over previous
//
#include <hip/hip_runtime.h>
#include <math.h>

#define RFL(x) __builtin_amdgcn_readfirstlane(x)
#define RL(x, l) __int_as_float(__builtin_amdgcn_readlane(__float_as_int(x), (l)))

typedef __attribute__((ext_vector_type(8))) short bf16x8;
typedef __attribute__((ext_vector_type(4))) float f32x4;

__device__ inline unsigned short bf16_rne(float f) {
  unsigned u = __float_as_uint(f);
  u += 0x7FFFu + ((u >> 16) & 1u);
  return (unsigned short)(u >> 16);
}

// ---------------- degree histogram (int) ----------------

__global__ __launch_bounds__(256) void k_zero(int* p, int n) {
  int t = blockIdx.x * 256 + threadIdx.x;
  if (t < n) p[t] = 0;
}

__global__ __launch_bounds__(256) void k_count(const int* __restrict__ dst, int* cnt, int E) {
  int stride = gridDim.x * blockDim.x;
  for (int e = blockIdx.x * blockDim.x + threadIdx.x; e < E; e += stride)
    atomicAdd(&cnt[dst[e]], 1);
}

// ---------------- exclusive scan: cnt -> row_start ----------------

__global__ __launch_bounds__(256) void k_scan1(const int* __restrict__ cnt, int* __restrict__ row,
                                               int* __restrict__ partial, int N) {
  __shared__ int sm[256];
  int t = threadIdx.x, g = blockIdx.x * 256 + t;
  int v = (g < N) ? cnt[g] : 0;
  sm[t] = v;
  __syncthreads();
#pragma unroll
  for (int off = 1; off < 256; off <<= 1) {
    int x = 0;
    if (t >= off) x = sm[t - off];
    __syncthreads();
    if (t >= off) sm[t] += x;
    __syncthreads();
  }
  if (g < N) row[g] = sm[t] - v;  // exclusive within block
  if (t == 255) partial[blockIdx.x] = sm[255];
}

__global__ __launch_bounds__(256) void k_scan2(int* __restrict__ partial, int P) {
  __shared__ int sm[256];
  int t = threadIdx.x;
  int carry = 0;
  for (int base = 0; base < P; base += 256) {
    int idx = base + t;
    int v = (idx < P) ? partial[idx] : 0;
    sm[t] = v;
    __syncthreads();
#pragma unroll
    for (int off = 1; off < 256; off <<= 1) {
      int x = 0;
      if (t >= off) x = sm[t - off];
      __syncthreads();
      if (t >= off) sm[t] += x;
      __syncthreads();
    }
    if (idx < P) partial[idx] = carry + sm[t] - v;  // exclusive
    int tot = sm[255];
    __syncthreads();
    carry += tot;
  }
}

// scan3 + dinv fused
__global__ __launch_bounds__(256) void k_scan3(int* __restrict__ row, const int* __restrict__ partial,
                                               int* __restrict__ cursor, const int* __restrict__ cnt,
                                               float* __restrict__ dinv, int N) {
  int g = blockIdx.x * 256 + threadIdx.x;
  if (g < N) {
    int v = row[g] + partial[blockIdx.x];
    row[g] = v;
    cursor[g] = v;
    dinv[g] = rsqrtf((float)cnt[g] + 1.0f);  // +1 self-loop
  }
}

// ---------------- edge placement: dst-sorted src ----------------

__global__ __launch_bounds__(256) void k_edge_fill(const int* __restrict__ src, const int* __restrict__ dst,
                                                   int* __restrict__ cursor, int* __restrict__ esrc, int E) {
  int stride = gridDim.x * blockDim.x;
  for (int e = blockIdx.x * blockDim.x + threadIdx.x; e < E; e += stride) {
    int s = src[e], d = dst[e];
    int pos = atomicAdd(&cursor[d], 1);
    esrc[pos] = s;
  }
}

// ---------------- W_c = W_out @ W1, b_c = b_out @ W1 ----------------

__global__ __launch_bounds__(256) void k_wc(const float* __restrict__ Wout, const float* __restrict__ bout,
                                            const float* __restrict__ W1, float* __restrict__ Wc,
                                            float* __restrict__ bc) {
  int t = blockIdx.x * 256 + threadIdx.x;
  if (t >= 65 * 128) return;
  int h = t >> 7, o = t & 127;
  const float* row = (h < 64) ? (Wout + h * 128) : bout;
  float a = 0.f;
  for (int d = 0; d < 128; ++d) a += row[d] * W1[d * 128 + o];
  if (h < 64) Wc[h * 128 + o] = a;
  else bc[o] = a;
}

// ---------------- attention pooling via MFMA (split-bf16), persistent+pipelined ----------------
// R14: epilogue now writes pzp = pooled * dinv[node] (GEMM commuted past the
// aggregation: x1 = Agg(pz)@Wc + g*bc, so gather runs in 64-dim space).

__global__ __launch_bounds__(256, 3) void k_pool(const float* __restrict__ X, const int* __restrict__ mask,
                                                 const float* __restrict__ WE, const float* __restrict__ bE,
                                                 const float* __restrict__ WA, const float* __restrict__ bA,
                                                 const float* __restrict__ dinv, float* __restrict__ pzp, int N) {
  __shared__ __align__(16) unsigned short Xh[80][136];
  __shared__ __align__(16) unsigned short Xl[80][136];
  __shared__ float scorep[80][4];
  __shared__ float sco[80];
  __shared__ float wgtA[80];
  float* zt = (float*)&Xh[0][0];  // alias: 80*68 f32 = 21760B = sizeof(Xh)

  const int t = threadIdx.x;
  const int lane = t & 63;
  const int wv = t >> 6;     // wave 0..3 = col tile
  const int cb = wv * 16;
  const int l16 = lane & 15;
  const int lg = lane >> 4;  // 0..3

  const long long totRows = (long long)N * 20;
  const int numTiles = (N + 3) / 4;

  const int r0 = t >> 5;            // rows r0, r0+8, ..., r0+72
  const int kq4 = (t & 31) * 4;     // float col base

  bf16x8 bh[4], bl[4];
#pragma unroll
  for (int kk = 0; kk < 4; ++kk) {
    union { bf16x8 v; unsigned short s[8]; } uh, ul;
#pragma unroll
    for (int i = 0; i < 8; ++i) {
      int k = kk * 32 + lg * 8 + i;
      float w = WE[k * 64 + cb + l16];
      unsigned short h = bf16_rne(w);
      uh.s[i] = h;
      ul.s[i] = bf16_rne(w - __uint_as_float((unsigned)h << 16));
    }
    bh[kk] = uh.v;
    bl[kk] = ul.v;
  }
  const float bEv = bE[cb + l16];
  const float WAv = WA[cb + l16];
  const float bAv = bA[0];
  const float NEG = -3.0e38f;

  int tile = blockIdx.x;
  if (tile >= numTiles) return;

  float4 xv[10];
#pragma unroll
  for (int q = 0; q < 10; ++q) {
    long long rr = (long long)tile * 80 + r0 + q * 8;
    if (rr >= totRows) rr = totRows - 1;
    xv[q] = *(const float4*)(X + rr * 128 + kq4);
  }
  int mkcur = 1;
  {
    long long mi = (long long)tile * 80 + t;
    if (t < 80) mkcur = (mi < totRows) ? mask[mi] : 0;
  }

  while (true) {
#pragma unroll
    for (int q = 0; q < 10; ++q) {
      const int r = r0 + q * 8;
      const float4 v = xv[q];
      unsigned short h0 = bf16_rne(v.x), h1 = bf16_rne(v.y), h2 = bf16_rne(v.z), h3 = bf16_rne(v.w);
      float f0 = __uint_as_float((unsigned)h0 << 16);
      float f1 = __uint_as_float((unsigned)h1 << 16);
      float f2 = __uint_as_float((unsigned)h2 << 16);
      float f3 = __uint_as_float((unsigned)h3 << 16);
      *(ushort4*)&Xh[r][kq4] = make_ushort4(h0, h1, h2, h3);
      *(ushort4*)&Xl[r][kq4] = make_ushort4(bf16_rne(v.x - f0), bf16_rne(v.y - f1),
                                            bf16_rne(v.z - f2), bf16_rne(v.w - f3));
    }
    __syncthreads();  // staging done

    const int nextTile = tile + gridDim.x;
    const bool hasNext = nextTile < numTiles;
    float4 xn[10];
    int mknext = 1;
    {
      const long long nb = (long long)(hasNext ? nextTile : tile) * 80;
#pragma unroll
      for (int q = 0; q < 10; ++q) {
        long long rr = nb + r0 + q * 8;
        if (rr >= totRows) rr = totRows - 1;
        xn[q] = *(const float4*)(X + rr * 128 + kq4);
      }
      long long mi = nb + t;
      if (t < 80) mknext = (mi < totRows) ? mask[mi] : 0;
    }

    f32x4 acc[5];
#pragma unroll
    for (int rt = 0; rt < 5; ++rt) acc[rt] = (f32x4){0.f, 0.f, 0.f, 0.f};
#pragma unroll
    for (int rt = 0; rt < 5; ++rt) {
      const int rl = rt * 16 + l16;
#pragma unroll
      for (int kk = 0; kk < 4; ++kk) {
        const int ko = kk * 32 + lg * 8;
        bf16x8 ah = *(const bf16x8*)&Xh[rl][ko];
        bf16x8 al = *(const bf16x8*)&Xl[rl][ko];
        acc[rt] = __builtin_amdgcn_mfma_f32_16x16x32_bf16(ah, bh[kk], acc[rt], 0, 0, 0);
        acc[rt] = __builtin_amdgcn_mfma_f32_16x16x32_bf16(ah, bl[kk], acc[rt], 0, 0, 0);
        acc[rt] = __builtin_amdgcn_mfma_f32_16x16x32_bf16(al, bh[kk], acc[rt], 0, 0, 0);
      }
    }

#pragma unroll
    for (int rt = 0; rt < 5; ++rt) {
#pragma unroll
      for (int j = 0; j < 4; ++j) {
        float z = fmaxf(acc[rt][j] + bEv, 0.f);
        acc[rt][j] = z;
        float v = z * WAv;
        v += __shfl_xor(v, 1, 64);
        v += __shfl_xor(v, 2, 64);
        v += __shfl_xor(v, 4, 64);
        v += __shfl_xor(v, 8, 64);
        if (l16 == 0) scorep[rt * 16 + lg * 4 + j][wv] = v;
      }
    }
    __syncthreads();  // barrier 1

#pragma unroll
    for (int rt = 0; rt < 5; ++rt) {
#pragma unroll
      for (int j = 0; j < 4; ++j) {
        int row = rt * 16 + lg * 4 + j;
        zt[row * 68 + cb + l16] = acc[rt][j];
      }
    }
    if (t < 80) {
      float4 sp = *(const float4*)scorep[t];
      float sc = sp.x + sp.y + sp.z + sp.w + bAv;
      if (mkcur == 0) sc = NEG;
      sco[t] = sc;
    }
    __syncthreads();  // barrier 2

    if (t < 80) {
      const int base = (t / 20) * 20;
      float mx = NEG;
#pragma unroll
      for (int i = 0; i < 20; ++i) mx = fmaxf(mx, sco[base + i]);
      float den = 0.f;
#pragma unroll
      for (int i = 0; i < 20; ++i) den += __expf(sco[base + i] - mx);
      wgtA[t] = __expf(sco[t] - mx) / den;
    }
    __syncthreads();  // barrier 3

    {
      int n = t >> 6, col = t & 63;
      long long node = (long long)tile * 4 + n;
      if (node < N) {
        float s = 0.f;
#pragma unroll
        for (int i = 0; i < 20; ++i) s += zt[(n * 20 + i) * 68 + col] * wgtA[n * 20 + i];
        pzp[node * 64 + col] = s * dinv[node];
      }
    }

    if (!hasNext) break;
    __syncthreads();  // barrier 4
#pragma unroll
    for (int q = 0; q < 10; ++q) xv[q] = xn[q];
    mkcur = mknext;
    tile = nextTile;
  }
}

// ---------------- gather layer 1 (64-dim): y[d] = dinv[d]*(sum_in pzp[s] + pzp[d]*dinv[d]) ----------------
// Also emits g[d] = dinv[d]*(sum_in dinv[s] + dinv[d]^2).
// 4 lane-groups x 4-deep contiguous edges = 16 float4 gathers in flight; masked tail.

__global__ __launch_bounds__(256) void k_gather1(const int* __restrict__ row, const int* __restrict__ cnt,
                                                 const int* __restrict__ esrc, const float* __restrict__ pzp,
                                                 const float* __restrict__ dinv, float* __restrict__ y,
                                                 float* __restrict__ gout, int N) {
  const int lane = threadIdx.x & 63;
  const int node = RFL(blockIdx.x * 4 + (threadIdx.x >> 6));
  if (node >= N) return;
  const int q = lane >> 4, f4 = lane & 15;  // group 0..3, float4 slot 0..15 (16x4=64 floats)
  const int rs = RFL(row[node]);
  const int ne = RFL(cnt[node]);
  const float di = dinv[node];
  const float4* __restrict__ hv = (const float4*)pzp;
  float a0 = 0.f, a1 = 0.f, a2 = 0.f, a3 = 0.f, ds = 0.f;
  int j = 0;
  for (; j + 16 <= ne; j += 16) {  // full chunk: group owns edges [j+4q, j+4q+4)
    const int b = rs + j + q * 4;
    int s[4];
#pragma unroll
    for (int u = 0; u < 4; ++u) s[u] = esrc[b + u];
    float4 v[4];
#pragma unroll
    for (int u = 0; u < 4; ++u) v[u] = hv[(size_t)s[u] * 16 + f4];
#pragma unroll
    for (int u = 0; u < 4; ++u) {
      a0 += v[u].x; a1 += v[u].y; a2 += v[u].z; a3 += v[u].w;
      ds += dinv[s[u]];  // group-uniform load (broadcast)
    }
  }
  if (j < ne) {  // partial chunk, masked
    const int b = j + q * 4;
    int s[4];
    float m[4];
#pragma unroll
    for (int u = 0; u < 4; ++u) {
      int idx = b + u;
      int c = (idx < ne) ? idx : (ne - 1);
      s[u] = esrc[rs + c];
      m[u] = (idx < ne) ? 1.f : 0.f;
    }
    float4 v[4];
#pragma unroll
    for (int u = 0; u < 4; ++u) v[u] = hv[(size_t)s[u] * 16 + f4];
#pragma unroll
    for (int u = 0; u < 4; ++u) {
      a0 += v[u].x * m[u]; a1 += v[u].y * m[u]; a2 += v[u].z * m[u]; a3 += v[u].w * m[u];
      ds += dinv[s[u]] * m[u];
    }
  }
  // cross-group combine (values group-uniform for ds; per-slot for a*)
  a0 += __shfl_xor(a0, 16, 64); a0 += __shfl_xor(a0, 32, 64);
  a1 += __shfl_xor(a1, 16, 64); a1 += __shfl_xor(a1, 32, 64);
  a2 += __shfl_xor(a2, 16, 64); a2 += __shfl_xor(a2, 32, 64);
  a3 += __shfl_xor(a3, 16, 64); a3 += __shfl_xor(a3, 32, 64);
  ds += __shfl_xor(ds, 16, 64); ds += __shfl_xor(ds, 32, 64);
  if (lane < 16) {
    float4 sv = hv[(size_t)node * 16 + f4];
    float4 o;
    o.x = (a0 + sv.x * di) * di;
    o.y = (a1 + sv.y * di) * di;
    o.z = (a2 + sv.z * di) * di;
    o.w = (a3 + sv.w * di) * di;
    ((float4*)y)[(size_t)node * 16 + f4] = o;
    if (f4 == 0) gout[node] = di * (ds + di * di);
  }
}

// ---------------- x1 = y @ Wc + g * bc ----------------
// wave per row; lane holds Wc[:,lane], Wc[:,lane+64]; y row broadcast via readlane.

__global__ __launch_bounds__(256, 2) void k_gemm1(const float* __restrict__ y, const float* __restrict__ gin,
                                                  const float* __restrict__ Wc, const float* __restrict__ bc,
                                                  float* __restrict__ x1, int N) {
  const int lane = threadIdx.x & 63;
  float w0[64], w1[64];
#pragma unroll
  for (int d = 0; d < 64; ++d) {
    w0[d] = Wc[d * 128 + lane];
    w1[d] = Wc[d * 128 + 64 + lane];
  }
  const float b0 = bc[lane], b1v = bc[64 + lane];
  const int nw = (gridDim.x * blockDim.x) >> 6;
  const int w_id = (blockIdx.x * blockDim.x + threadIdx.x) >> 6;
  for (int r = w_id; r < N; r += nw) {
    const float xv = y[(size_t)r * 64 + lane];
    const float gr = gin[r];
    const int xi = __float_as_int(xv);
    float p0 = 0.f, p1 = 0.f, p2 = 0.f, p3 = 0.f;
#pragma unroll
    for (int d0 = 0; d0 < 64; d0 += 2) {
      float a0 = RL((float&)xi, d0);
      float a1 = RL((float&)xi, d0 + 1);
      p0 += a0 * w0[d0];
      p1 += a0 * w1[d0];
      p2 += a1 * w0[d0 + 1];
      p3 += a1 * w1[d0 + 1];
    }
    size_t o = (size_t)r * 128 + lane;
    x1[o] = p0 + p2 + gr * b0;
    x1[o + 64] = p1 + p3 + gr * b1v;
  }
}

// ---------------- h2p = (relu(x1 + b1) @ W2) * dinv[r] ----------------

__global__ __launch_bounds__(256, 2) void k_gemm2(const float* __restrict__ x1, const float* __restrict__ b1,
                                                  const float* __restrict__ W2, const float* __restrict__ dinv,
                                                  float* __restrict__ h2p, int N) {
  const int lane = threadIdx.x & 63;
  const int col = lane & 31;
  float w[128];
#pragma unroll
  for (int d = 0; d < 128; ++d) w[d] = W2[d * 32 + col];
  const float bb0 = b1[lane], bb1 = b1[64 + lane];
  const int nw = (gridDim.x * blockDim.x) >> 6;
  const int w_id = (blockIdx.x * blockDim.x + threadIdx.x) >> 6;
  for (int r = w_id; r < N; r += nw) {
    float rx0 = fmaxf(x1[(size_t)r * 128 + lane] + bb0, 0.f);
    float rx1 = fmaxf(x1[(size_t)r * 128 + 64 + lane] + bb1, 0.f);
    const int xi0 = __float_as_int(rx0), xi1 = __float_as_int(rx1);
    float p0 = 0.f, p1 = 0.f, p2 = 0.f, p3 = 0.f;
#pragma unroll
    for (int d0 = 0; d0 < 64; d0 += 2) {
      float a0 = RL((float&)xi0, d0);
      float a1 = RL((float&)xi0, d0 + 1);
      float c0 = RL((float&)xi1, d0);
      float c1 = RL((float&)xi1, d0 + 1);
      p0 += a0 * w[d0];
      p1 += a1 * w[d0 + 1];
      p2 += c0 * w[64 + d0];
      p3 += c1 * w[64 + d0 + 1];
    }
    if (lane < 32) {
      float di = dinv[r];
      h2p[(size_t)r * 32 + col] = ((p0 + p1) + (p2 + p3)) * di;
    }
  }
}

// ---------------- gather layer 2: 32-edge chunks; group q owns 4 contiguous edges ----------------

__global__ __launch_bounds__(256) void k_gather2(const int* __restrict__ row, const int* __restrict__ cnt,
                                                 const int* __restrict__ esrc, const float* __restrict__ h2p,
                                                 const float* __restrict__ dinv, float* __restrict__ x2, int N) {
  const int lane = threadIdx.x & 63;
  const int node = RFL(blockIdx.x * 4 + (threadIdx.x >> 6));
  if (node >= N) return;
  const int q = lane >> 3, f4 = lane & 7;  // group 0..7, float4 slot 0..7 (8x4=32 floats)
  const int rs = RFL(row[node]);
  const int ne = RFL(cnt[node]);
  const float di = dinv[node];
  const float4* __restrict__ hv = (const float4*)h2p;
  float a0 = 0.f, a1 = 0.f, a2 = 0.f, a3 = 0.f;
  int j = 0;
  for (; j + 32 <= ne; j += 32) {
    const int b = rs + j + q * 4;
    int s[4];
#pragma unroll
    for (int u = 0; u < 4; ++u) s[u] = esrc[b + u];
    float4 v[4];
#pragma unroll
    for (int u = 0; u < 4; ++u) v[u] = hv[(size_t)s[u] * 8 + f4];
#pragma unroll
    for (int u = 0; u < 4; ++u) {
      a0 += v[u].x; a1 += v[u].y; a2 += v[u].z; a3 += v[u].w;
    }
  }
  if (j < ne) {
    const int b = j + q * 4;
    int s[4];
    float m[4];
#pragma unroll
    for (int u = 0; u < 4; ++u) {
      int idx = b + u;
      int c = (idx < ne) ? idx : (ne - 1);
      s[u] = esrc[rs + c];
      m[u] = (idx < ne) ? 1.f : 0.f;
    }
    float4 v[4];
#pragma unroll
    for (int u = 0; u < 4; ++u) v[u] = hv[(size_t)s[u] * 8 + f4];
#pragma unroll
    for (int u = 0; u < 4; ++u) {
      a0 += v[u].x * m[u]; a1 += v[u].y * m[u]; a2 += v[u].z * m[u]; a3 += v[u].w * m[u];
    }
  }
#pragma unroll
  for (int off = 8; off <= 32; off <<= 1) {
    a0 += __shfl_xor(a0, off, 64);
    a1 += __shfl_xor(a1, off, 64);
    a2 += __shfl_xor(a2, off, 64);
    a3 += __shfl_xor(a3, off, 64);
  }
  if (q == 0) {
    float4 sv = hv[(size_t)node * 8 + f4];
    float4 o;
    o.x = (a0 + sv.x * di) * di;
    o.y = (a1 + sv.y * di) * di;
    o.z = (a2 + sv.z * di) * di;
    o.w = (a3 + sv.w * di) * di;
    ((float4*)x2)[(size_t)node * 8 + f4] = o;
  }
}

// ---------------- query MLP ----------------

__global__ __launch_bounds__(256) void k_mlp(const int* __restrict__ qidx, const float* __restrict__ x2,
                                             const float* __restrict__ b2, const float* __restrict__ Wm1,
                                             const float* __restrict__ bm1, const float* __restrict__ Wm2,
                                             const float* __restrict__ bm2, float* __restrict__ out, int B) {
  int t = blockIdx.x * 256 + threadIdx.x;
  if (t >= B) return;
  int n = qidx[t];
  float qv[32];
#pragma unroll
  for (int k = 0; k < 32; ++k) qv[k] = fmaxf(x2[(size_t)n * 32 + k] + b2[k], 0.f);
  float acc = bm2[0];
  for (int j = 0; j < 64; ++j) {
    float h = bm1[j];
#pragma unroll
    for (int k = 0; k < 32; ++k) h += qv[k] * Wm1[k * 64 + j];
    acc += fmaxf(h, 0.f) * Wm2[j];
  }
  out[t] = acc;
}

// ---------------- launcher ----------------

extern "C" void kernel_launch(void* const* d_in, const int* in_sizes, int n_in,
                              void* d_out, int out_size, void* d_ws, size_t ws_size,
                              hipStream_t stream) {
  const float* X    = (const float*)d_in[0];
  const int*   mask = (const int*)d_in[1];
  const int*   ei   = (const int*)d_in[2];
  const int*   qidx = (const int*)d_in[3];
  const float* WE   = (const float*)d_in[4];
  const float* bE   = (const float*)d_in[5];
  const float* WA   = (const float*)d_in[6];
  const float* bA   = (const float*)d_in[7];
  const float* Wout = (const float*)d_in[8];
  const float* bout = (const float*)d_in[9];
  const float* W1   = (const float*)d_in[10];
  const float* b1   = (const float*)d_in[11];
  const float* W2   = (const float*)d_in[12];
  const float* b2   = (const float*)d_in[13];
  const float* Wm1  = (const float*)d_in[14];
  const float* bm1  = (const float*)d_in[15];
  const float* Wm2  = (const float*)d_in[16];
  const float* bm2  = (const float*)d_in[17];

  const int N = in_sizes[1] / 20;
  const int E = in_sizes[2] / 2;
  const int B = in_sizes[3];
  const int* src  = ei;
  const int* dstp = ei + E;

  const size_t Na = ((size_t)N + 63) & ~(size_t)63;
  const size_t Ea = ((size_t)E + 63) & ~(size_t)63;
  const int P = (N + 255) / 256;
  const size_t Pa = ((size_t)P + 63) & ~(size_t)63;

  float* ws      = (float*)d_ws;
  float* dinv    = ws;                       // N
  int*   cnt     = (int*)(dinv + Na);        // N
  int*   rowp    = cnt + Na;                 // N
  int*   cursor  = rowp + Na;                // N
  int*   partial = cursor + Na;              // P
  int*   esrc    = partial + Pa;             // E
  float* Wc      = (float*)(esrc + Ea);      // 8192
  float* bc      = Wc + 8192;                // 128
  float* gbuf    = bc + 128;                 // N
  float* pzp     = gbuf + Na;                // N*64
  float* y       = pzp + (size_t)N * 64;     // N*64
  float* x1      = y + (size_t)N * 64;       // N*128
  float* h2p     = pzp;                      // reuse pzp (dead after gather1+gemm1... dead after gather1): N*32
  float* x2      = pzp + (size_t)N * 32;     // N*32

  const int nb = (N + 255) / 256;
  const int nw4 = (N + 3) / 4;
  const int poolBlocks = ((N + 3) / 4 < 768) ? (N + 3) / 4 : 768;

  k_zero<<<nb, 256, 0, stream>>>(cnt, N);
  k_count<<<1024, 256, 0, stream>>>(dstp, cnt, E);
  k_scan1<<<P, 256, 0, stream>>>(cnt, rowp, partial, N);
  k_scan2<<<1, 256, 0, stream>>>(partial, P);
  k_scan3<<<P, 256, 0, stream>>>(rowp, partial, cursor, cnt, dinv, N);
  k_edge_fill<<<1024, 256, 0, stream>>>(src, dstp, cursor, esrc, E);
  k_wc<<<33, 256, 0, stream>>>(Wout, bout, W1, Wc, bc);
  k_pool<<<poolBlocks, 256, 0, stream>>>(X, mask, WE, bE, WA, bA, dinv, pzp, N);
  k_gather1<<<nw4, 256, 0, stream>>>(rowp, cnt, esrc, pzp, dinv, y, gbuf, N);
  k_gemm1<<<1024, 256, 0, stream>>>(y, gbuf, Wc, bc, x1, N);
  k_gemm2<<<1024, 256, 0, stream>>>(x1, b1, W2, dinv, h2p, N);
  k_gather2<<<nw4, 256, 0, stream>>>(rowp, cnt, esrc, h2p, dinv, x2, N);
  k_mlp<<<(B + 255) / 256, 256, 0, stream>>>(qidx, x2, b2, Wm1, bm1, Wm2, bm2, (float*)d_out, B);
}

// Round 15
// 476.198 us; speedup vs baseline: 1.6663x; 1.0719x over previous
//
#include <hip/hip_runtime.h>
#include <math.h>

#define RFL(x) __builtin_amdgcn_readfirstlane(x)
#define RL(x, l) __int_as_float(__builtin_amdgcn_readlane(__float_as_int(x), (l)))

typedef __attribute__((ext_vector_type(8))) short bf16x8;
typedef __attribute__((ext_vector_type(4))) float f32x4;

__device__ inline unsigned short bf16_rne(float f) {
  unsigned u = __float_as_uint(f);
  u += 0x7FFFu + ((u >> 16) & 1u);
  return (unsigned short)(u >> 16);
}

// ---------------- degree histogram (int) ----------------

__global__ __launch_bounds__(256) void k_zero(int* p, int n) {
  int t = blockIdx.x * 256 + threadIdx.x;
  if (t < n) p[t] = 0;
}

__global__ __launch_bounds__(256) void k_count(const int* __restrict__ dst, int* cnt, int E) {
  int stride = gridDim.x * blockDim.x;
  for (int e = blockIdx.x * blockDim.x + threadIdx.x; e < E; e += stride)
    atomicAdd(&cnt[dst[e]], 1);
}

// ---------------- exclusive scan: cnt -> row_start ----------------

__global__ __launch_bounds__(256) void k_scan1(const int* __restrict__ cnt, int* __restrict__ row,
                                               int* __restrict__ partial, int N) {
  __shared__ int sm[256];
  int t = threadIdx.x, g = blockIdx.x * 256 + t;
  int v = (g < N) ? cnt[g] : 0;
  sm[t] = v;
  __syncthreads();
#pragma unroll
  for (int off = 1; off < 256; off <<= 1) {
    int x = 0;
    if (t >= off) x = sm[t - off];
    __syncthreads();
    if (t >= off) sm[t] += x;
    __syncthreads();
  }
  if (g < N) row[g] = sm[t] - v;  // exclusive within block
  if (t == 255) partial[blockIdx.x] = sm[255];
}

__global__ __launch_bounds__(256) void k_scan2(int* __restrict__ partial, int P) {
  __shared__ int sm[256];
  int t = threadIdx.x;
  int carry = 0;
  for (int base = 0; base < P; base += 256) {
    int idx = base + t;
    int v = (idx < P) ? partial[idx] : 0;
    sm[t] = v;
    __syncthreads();
#pragma unroll
    for (int off = 1; off < 256; off <<= 1) {
      int x = 0;
      if (t >= off) x = sm[t - off];
      __syncthreads();
      if (t >= off) sm[t] += x;
      __syncthreads();
    }
    if (idx < P) partial[idx] = carry + sm[t] - v;  // exclusive
    int tot = sm[255];
    __syncthreads();
    carry += tot;
  }
}

// scan3 + dinv fused
__global__ __launch_bounds__(256) void k_scan3(int* __restrict__ row, const int* __restrict__ partial,
                                               int* __restrict__ cursor, const int* __restrict__ cnt,
                                               float* __restrict__ dinv, int N) {
  int g = blockIdx.x * 256 + threadIdx.x;
  if (g < N) {
    int v = row[g] + partial[blockIdx.x];
    row[g] = v;
    cursor[g] = v;
    dinv[g] = rsqrtf((float)cnt[g] + 1.0f);  // +1 self-loop
  }
}

// ---------------- edge placement: dst-sorted src ----------------

__global__ __launch_bounds__(256) void k_edge_fill(const int* __restrict__ src, const int* __restrict__ dst,
                                                   int* __restrict__ cursor, int* __restrict__ esrc, int E) {
  int stride = gridDim.x * blockDim.x;
  for (int e = blockIdx.x * blockDim.x + threadIdx.x; e < E; e += stride) {
    int s = src[e], d = dst[e];
    int pos = atomicAdd(&cursor[d], 1);
    esrc[pos] = s;
  }
}

// ---------------- W_c = W_out @ W1, b_c = b_out @ W1 ----------------

__global__ __launch_bounds__(256) void k_wc(const float* __restrict__ Wout, const float* __restrict__ bout,
                                            const float* __restrict__ W1, float* __restrict__ Wc,
                                            float* __restrict__ bc) {
  int t = blockIdx.x * 256 + threadIdx.x;
  if (t >= 65 * 128) return;
  int h = t >> 7, o = t & 127;
  const float* row = (h < 64) ? (Wout + h * 128) : bout;
  float a = 0.f;
  for (int d = 0; d < 128; ++d) a += row[d] * W1[d * 128 + o];
  if (h < 64) Wc[h * 128 + o] = a;
  else bc[o] = a;
}

// ---------------- attention pooling via MFMA (split-bf16), persistent+pipelined ----------------
// (unchanged from R14)

__global__ __launch_bounds__(256, 3) void k_pool(const float* __restrict__ X, const int* __restrict__ mask,
                                                 const float* __restrict__ WE, const float* __restrict__ bE,
                                                 const float* __restrict__ WA, const float* __restrict__ bA,
                                                 const float* __restrict__ dinv, float* __restrict__ pzp, int N) {
  __shared__ __align__(16) unsigned short Xh[80][136];
  __shared__ __align__(16) unsigned short Xl[80][136];
  __shared__ float scorep[80][4];
  __shared__ float sco[80];
  __shared__ float wgtA[80];
  float* zt = (float*)&Xh[0][0];  // alias: 80*68 f32 = 21760B = sizeof(Xh)

  const int t = threadIdx.x;
  const int lane = t & 63;
  const int wv = t >> 6;     // wave 0..3 = col tile
  const int cb = wv * 16;
  const int l16 = lane & 15;
  const int lg = lane >> 4;  // 0..3

  const long long totRows = (long long)N * 20;
  const int numTiles = (N + 3) / 4;

  const int r0 = t >> 5;            // rows r0, r0+8, ..., r0+72
  const int kq4 = (t & 31) * 4;     // float col base

  bf16x8 bh[4], bl[4];
#pragma unroll
  for (int kk = 0; kk < 4; ++kk) {
    union { bf16x8 v; unsigned short s[8]; } uh, ul;
#pragma unroll
    for (int i = 0; i < 8; ++i) {
      int k = kk * 32 + lg * 8 + i;
      float w = WE[k * 64 + cb + l16];
      unsigned short h = bf16_rne(w);
      uh.s[i] = h;
      ul.s[i] = bf16_rne(w - __uint_as_float((unsigned)h << 16));
    }
    bh[kk] = uh.v;
    bl[kk] = ul.v;
  }
  const float bEv = bE[cb + l16];
  const float WAv = WA[cb + l16];
  const float bAv = bA[0];
  const float NEG = -3.0e38f;

  int tile = blockIdx.x;
  if (tile >= numTiles) return;

  float4 xv[10];
#pragma unroll
  for (int q = 0; q < 10; ++q) {
    long long rr = (long long)tile * 80 + r0 + q * 8;
    if (rr >= totRows) rr = totRows - 1;
    xv[q] = *(const float4*)(X + rr * 128 + kq4);
  }
  int mkcur = 1;
  {
    long long mi = (long long)tile * 80 + t;
    if (t < 80) mkcur = (mi < totRows) ? mask[mi] : 0;
  }

  while (true) {
#pragma unroll
    for (int q = 0; q < 10; ++q) {
      const int r = r0 + q * 8;
      const float4 v = xv[q];
      unsigned short h0 = bf16_rne(v.x), h1 = bf16_rne(v.y), h2 = bf16_rne(v.z), h3 = bf16_rne(v.w);
      float f0 = __uint_as_float((unsigned)h0 << 16);
      float f1 = __uint_as_float((unsigned)h1 << 16);
      float f2 = __uint_as_float((unsigned)h2 << 16);
      float f3 = __uint_as_float((unsigned)h3 << 16);
      *(ushort4*)&Xh[r][kq4] = make_ushort4(h0, h1, h2, h3);
      *(ushort4*)&Xl[r][kq4] = make_ushort4(bf16_rne(v.x - f0), bf16_rne(v.y - f1),
                                            bf16_rne(v.z - f2), bf16_rne(v.w - f3));
    }
    __syncthreads();  // staging done

    const int nextTile = tile + gridDim.x;
    const bool hasNext = nextTile < numTiles;
    float4 xn[10];
    int mknext = 1;
    {
      const long long nb = (long long)(hasNext ? nextTile : tile) * 80;
#pragma unroll
      for (int q = 0; q < 10; ++q) {
        long long rr = nb + r0 + q * 8;
        if (rr >= totRows) rr = totRows - 1;
        xn[q] = *(const float4*)(X + rr * 128 + kq4);
      }
      long long mi = nb + t;
      if (t < 80) mknext = (mi < totRows) ? mask[mi] : 0;
    }

    f32x4 acc[5];
#pragma unroll
    for (int rt = 0; rt < 5; ++rt) acc[rt] = (f32x4){0.f, 0.f, 0.f, 0.f};
#pragma unroll
    for (int rt = 0; rt < 5; ++rt) {
      const int rl = rt * 16 + l16;
#pragma unroll
      for (int kk = 0; kk < 4; ++kk) {
        const int ko = kk * 32 + lg * 8;
        bf16x8 ah = *(const bf16x8*)&Xh[rl][ko];
        bf16x8 al = *(const bf16x8*)&Xl[rl][ko];
        acc[rt] = __builtin_amdgcn_mfma_f32_16x16x32_bf16(ah, bh[kk], acc[rt], 0, 0, 0);
        acc[rt] = __builtin_amdgcn_mfma_f32_16x16x32_bf16(ah, bl[kk], acc[rt], 0, 0, 0);
        acc[rt] = __builtin_amdgcn_mfma_f32_16x16x32_bf16(al, bh[kk], acc[rt], 0, 0, 0);
      }
    }

#pragma unroll
    for (int rt = 0; rt < 5; ++rt) {
#pragma unroll
      for (int j = 0; j < 4; ++j) {
        float z = fmaxf(acc[rt][j] + bEv, 0.f);
        acc[rt][j] = z;
        float v = z * WAv;
        v += __shfl_xor(v, 1, 64);
        v += __shfl_xor(v, 2, 64);
        v += __shfl_xor(v, 4, 64);
        v += __shfl_xor(v, 8, 64);
        if (l16 == 0) scorep[rt * 16 + lg * 4 + j][wv] = v;
      }
    }
    __syncthreads();  // barrier 1

#pragma unroll
    for (int rt = 0; rt < 5; ++rt) {
#pragma unroll
      for (int j = 0; j < 4; ++j) {
        int row = rt * 16 + lg * 4 + j;
        zt[row * 68 + cb + l16] = acc[rt][j];
      }
    }
    if (t < 80) {
      float4 sp = *(const float4*)scorep[t];
      float sc = sp.x + sp.y + sp.z + sp.w + bAv;
      if (mkcur == 0) sc = NEG;
      sco[t] = sc;
    }
    __syncthreads();  // barrier 2

    if (t < 80) {
      const int base = (t / 20) * 20;
      float mx = NEG;
#pragma unroll
      for (int i = 0; i < 20; ++i) mx = fmaxf(mx, sco[base + i]);
      float den = 0.f;
#pragma unroll
      for (int i = 0; i < 20; ++i) den += __expf(sco[base + i] - mx);
      wgtA[t] = __expf(sco[t] - mx) / den;
    }
    __syncthreads();  // barrier 3

    {
      int n = t >> 6, col = t & 63;
      long long node = (long long)tile * 4 + n;
      if (node < N) {
        float s = 0.f;
#pragma unroll
        for (int i = 0; i < 20; ++i) s += zt[(n * 20 + i) * 68 + col] * wgtA[n * 20 + i];
        pzp[node * 64 + col] = s * dinv[node];
      }
    }

    if (!hasNext) break;
    __syncthreads();  // barrier 4
#pragma unroll
    for (int q = 0; q < 10; ++q) xv[q] = xn[q];
    mkcur = mknext;
    tile = nextTile;
  }
}

// ---------------- gather layer 1 (64-dim) + g vector ----------------

__global__ __launch_bounds__(256) void k_gather1(const int* __restrict__ row, const int* __restrict__ cnt,
                                                 const int* __restrict__ esrc, const float* __restrict__ pzp,
                                                 const float* __restrict__ dinv, float* __restrict__ y,
                                                 float* __restrict__ gout, int N) {
  const int lane = threadIdx.x & 63;
  const int node = RFL(blockIdx.x * 4 + (threadIdx.x >> 6));
  if (node >= N) return;
  const int q = lane >> 4, f4 = lane & 15;  // group 0..3, float4 slot 0..15
  const int rs = RFL(row[node]);
  const int ne = RFL(cnt[node]);
  const float di = dinv[node];
  const float4* __restrict__ hv = (const float4*)pzp;
  float a0 = 0.f, a1 = 0.f, a2 = 0.f, a3 = 0.f, ds = 0.f;
  int j = 0;
  for (; j + 16 <= ne; j += 16) {
    const int b = rs + j + q * 4;
    int s[4];
#pragma unroll
    for (int u = 0; u < 4; ++u) s[u] = esrc[b + u];
    float4 v[4];
#pragma unroll
    for (int u = 0; u < 4; ++u) v[u] = hv[(size_t)s[u] * 16 + f4];
#pragma unroll
    for (int u = 0; u < 4; ++u) {
      a0 += v[u].x; a1 += v[u].y; a2 += v[u].z; a3 += v[u].w;
      ds += dinv[s[u]];
    }
  }
  if (j < ne) {
    const int b = j + q * 4;
    int s[4];
    float m[4];
#pragma unroll
    for (int u = 0; u < 4; ++u) {
      int idx = b + u;
      int c = (idx < ne) ? idx : (ne - 1);
      s[u] = esrc[rs + c];
      m[u] = (idx < ne) ? 1.f : 0.f;
    }
    float4 v[4];
#pragma unroll
    for (int u = 0; u < 4; ++u) v[u] = hv[(size_t)s[u] * 16 + f4];
#pragma unroll
    for (int u = 0; u < 4; ++u) {
      a0 += v[u].x * m[u]; a1 += v[u].y * m[u]; a2 += v[u].z * m[u]; a3 += v[u].w * m[u];
      ds += dinv[s[u]] * m[u];
    }
  }
  a0 += __shfl_xor(a0, 16, 64); a0 += __shfl_xor(a0, 32, 64);
  a1 += __shfl_xor(a1, 16, 64); a1 += __shfl_xor(a1, 32, 64);
  a2 += __shfl_xor(a2, 16, 64); a2 += __shfl_xor(a2, 32, 64);
  a3 += __shfl_xor(a3, 16, 64); a3 += __shfl_xor(a3, 32, 64);
  ds += __shfl_xor(ds, 16, 64); ds += __shfl_xor(ds, 32, 64);
  if (lane < 16) {
    float4 sv = hv[(size_t)node * 16 + f4];
    float4 o;
    o.x = (a0 + sv.x * di) * di;
    o.y = (a1 + sv.y * di) * di;
    o.z = (a2 + sv.z * di) * di;
    o.w = (a3 + sv.w * di) * di;
    ((float4*)y)[(size_t)node * 16 + f4] = o;
    if (f4 == 0) gout[node] = di * (ds + di * di);
  }
}

// ---------------- x1 = y @ Wc + g * bc ----------------

__global__ __launch_bounds__(256, 2) void k_gemm1(const float* __restrict__ y, const float* __restrict__ gin,
                                                  const float* __restrict__ Wc, const float* __restrict__ bc,
                                                  float* __restrict__ x1, int N) {
  const int lane = threadIdx.x & 63;
  float w0[64], w1[64];
#pragma unroll
  for (int d = 0; d < 64; ++d) {
    w0[d] = Wc[d * 128 + lane];
    w1[d] = Wc[d * 128 + 64 + lane];
  }
  const float b0 = bc[lane], b1v = bc[64 + lane];
  const int nw = (gridDim.x * blockDim.x) >> 6;
  const int w_id = (blockIdx.x * blockDim.x + threadIdx.x) >> 6;
  for (int r = w_id; r < N; r += nw) {
    const float xv = y[(size_t)r * 64 + lane];
    const float gr = gin[r];
    const int xi = __float_as_int(xv);
    float p0 = 0.f, p1 = 0.f, p2 = 0.f, p3 = 0.f;
#pragma unroll
    for (int d0 = 0; d0 < 64; d0 += 2) {
      float a0 = RL((float&)xi, d0);
      float a1 = RL((float&)xi, d0 + 1);
      p0 += a0 * w0[d0];
      p1 += a0 * w1[d0];
      p2 += a1 * w0[d0 + 1];
      p3 += a1 * w1[d0 + 1];
    }
    size_t o = (size_t)r * 128 + lane;
    x1[o] = p0 + p2 + gr * b0;
    x1[o + 64] = p1 + p3 + gr * b1v;
  }
}

// ---------------- h2p = (relu(x1 + b1) @ W2) * dinv[r] ----------------

__global__ __launch_bounds__(256, 2) void k_gemm2(const float* __restrict__ x1, const float* __restrict__ b1,
                                                  const float* __restrict__ W2, const float* __restrict__ dinv,
                                                  float* __restrict__ h2p, int N) {
  const int lane = threadIdx.x & 63;
  const int col = lane & 31;
  float w[128];
#pragma unroll
  for (int d = 0; d < 128; ++d) w[d] = W2[d * 32 + col];
  const float bb0 = b1[lane], bb1 = b1[64 + lane];
  const int nw = (gridDim.x * blockDim.x) >> 6;
  const int w_id = (blockIdx.x * blockDim.x + threadIdx.x) >> 6;
  for (int r = w_id; r < N; r += nw) {
    float rx0 = fmaxf(x1[(size_t)r * 128 + lane] + bb0, 0.f);
    float rx1 = fmaxf(x1[(size_t)r * 128 + 64 + lane] + bb1, 0.f);
    const int xi0 = __float_as_int(rx0), xi1 = __float_as_int(rx1);
    float p0 = 0.f, p1 = 0.f, p2 = 0.f, p3 = 0.f;
#pragma unroll
    for (int d0 = 0; d0 < 64; d0 += 2) {
      float a0 = RL((float&)xi0, d0);
      float a1 = RL((float&)xi0, d0 + 1);
      float c0 = RL((float&)xi1, d0);
      float c1 = RL((float&)xi1, d0 + 1);
      p0 += a0 * w[d0];
      p1 += a1 * w[d0 + 1];
      p2 += c0 * w[64 + d0];
      p3 += c1 * w[64 + d0 + 1];
    }
    if (lane < 32) {
      float di = dinv[r];
      h2p[(size_t)r * 32 + col] = ((p0 + p1) + (p2 + p3)) * di;
    }
  }
}

// ---------------- fused layer-2 gather + query MLP (per-query; 12x less aggregation) ----------------
// One wave per query. Gather x2 for node=qidx[w] (gather2's proven chunked form,
// 8 groups x 4-deep), relu(x2+b2) -> 32 floats via per-wave LDS -> wave-parallel
// MLP (lane j owns hidden j; Wm1 column loads L1-hot) -> shfl-tree reduce.

__global__ __launch_bounds__(256) void k_gmlp(const int* __restrict__ qidx, const int* __restrict__ row,
                                              const int* __restrict__ cnt, const int* __restrict__ esrc,
                                              const float* __restrict__ h2p, const float* __restrict__ dinv,
                                              const float* __restrict__ b2, const float* __restrict__ Wm1,
                                              const float* __restrict__ bm1, const float* __restrict__ Wm2,
                                              const float* __restrict__ bm2, float* __restrict__ out, int B) {
  __shared__ float qs[4][32];
  const int lane = threadIdx.x & 63;
  const int wv = threadIdx.x >> 6;
  const int w = blockIdx.x * 4 + wv;            // query id
  const int wc = (w < B) ? w : (B - 1);         // clamp (keep block barrier-uniform)
  const int node = RFL(qidx[wc]);

  const int q = lane >> 3, f4 = lane & 7;       // group 0..7, float4 slot 0..7
  const int rs = RFL(row[node]);
  const int ne = RFL(cnt[node]);
  const float di = dinv[node];
  const float4* __restrict__ hv = (const float4*)h2p;
  float a0 = 0.f, a1 = 0.f, a2 = 0.f, a3 = 0.f;
  int j = 0;
  for (; j + 32 <= ne; j += 32) {
    const int b = rs + j + q * 4;
    int s[4];
#pragma unroll
    for (int u = 0; u < 4; ++u) s[u] = esrc[b + u];
    float4 v[4];
#pragma unroll
    for (int u = 0; u < 4; ++u) v[u] = hv[(size_t)s[u] * 8 + f4];
#pragma unroll
    for (int u = 0; u < 4; ++u) {
      a0 += v[u].x; a1 += v[u].y; a2 += v[u].z; a3 += v[u].w;
    }
  }
  if (j < ne) {
    const int b = j + q * 4;
    int s[4];
    float m[4];
#pragma unroll
    for (int u = 0; u < 4; ++u) {
      int idx = b + u;
      int c = (idx < ne) ? idx : (ne - 1);
      s[u] = esrc[rs + c];
      m[u] = (idx < ne) ? 1.f : 0.f;
    }
    float4 v[4];
#pragma unroll
    for (int u = 0; u < 4; ++u) v[u] = hv[(size_t)s[u] * 8 + f4];
#pragma unroll
    for (int u = 0; u < 4; ++u) {
      a0 += v[u].x * m[u]; a1 += v[u].y * m[u]; a2 += v[u].z * m[u]; a3 += v[u].w * m[u];
    }
  }
#pragma unroll
  for (int off = 8; off <= 32; off <<= 1) {
    a0 += __shfl_xor(a0, off, 64);
    a1 += __shfl_xor(a1, off, 64);
    a2 += __shfl_xor(a2, off, 64);
    a3 += __shfl_xor(a3, off, 64);
  }
  if (q == 0) {  // lanes 0..7 hold the final x2 float4s
    float4 sv = hv[(size_t)node * 8 + f4];
    qs[wv][f4 * 4 + 0] = fmaxf((a0 + sv.x * di) * di + b2[f4 * 4 + 0], 0.f);
    qs[wv][f4 * 4 + 1] = fmaxf((a1 + sv.y * di) * di + b2[f4 * 4 + 1], 0.f);
    qs[wv][f4 * 4 + 2] = fmaxf((a2 + sv.z * di) * di + b2[f4 * 4 + 2], 0.f);
    qs[wv][f4 * 4 + 3] = fmaxf((a3 + sv.w * di) * di + b2[f4 * 4 + 3], 0.f);
  }
  __syncthreads();

  // lane j computes hidden unit j
  float h = bm1[lane];
#pragma unroll
  for (int k = 0; k < 32; ++k) h += qs[wv][k] * Wm1[k * 64 + lane];
  float r = fmaxf(h, 0.f) * Wm2[lane];
#pragma unroll
  for (int off = 1; off < 64; off <<= 1) r += __shfl_xor(r, off, 64);
  if (lane == 0 && w < B) out[w] = r + bm2[0];
}

// ---------------- launcher ----------------

extern "C" void kernel_launch(void* const* d_in, const int* in_sizes, int n_in,
                              void* d_out, int out_size, void* d_ws, size_t ws_size,
                              hipStream_t stream) {
  const float* X    = (const float*)d_in[0];
  const int*   mask = (const int*)d_in[1];
  const int*   ei   = (const int*)d_in[2];
  const int*   qidx = (const int*)d_in[3];
  const float* WE   = (const float*)d_in[4];
  const float* bE   = (const float*)d_in[5];
  const float* WA   = (const float*)d_in[6];
  const float* bA   = (const float*)d_in[7];
  const float* Wout = (const float*)d_in[8];
  const float* bout = (const float*)d_in[9];
  const float* W1   = (const float*)d_in[10];
  const float* b1   = (const float*)d_in[11];
  const float* W2   = (const float*)d_in[12];
  const float* b2   = (const float*)d_in[13];
  const float* Wm1  = (const float*)d_in[14];
  const float* bm1  = (const float*)d_in[15];
  const float* Wm2  = (const float*)d_in[16];
  const float* bm2  = (const float*)d_in[17];

  const int N = in_sizes[1] / 20;
  const int E = in_sizes[2] / 2;
  const int B = in_sizes[3];
  const int* src  = ei;
  const int* dstp = ei + E;

  const size_t Na = ((size_t)N + 63) & ~(size_t)63;
  const size_t Ea = ((size_t)E + 63) & ~(size_t)63;
  const int P = (N + 255) / 256;
  const size_t Pa = ((size_t)P + 63) & ~(size_t)63;

  float* ws      = (float*)d_ws;
  float* dinv    = ws;                       // N
  int*   cnt     = (int*)(dinv + Na);        // N
  int*   rowp    = cnt + Na;                 // N
  int*   cursor  = rowp + Na;                // N
  int*   partial = cursor + Na;              // P
  int*   esrc    = partial + Pa;             // E
  float* Wc      = (float*)(esrc + Ea);      // 8192
  float* bc      = Wc + 8192;                // 128
  float* gbuf    = bc + 128;                 // N
  float* pzp     = gbuf + Na;                // N*64
  float* y       = pzp + (size_t)N * 64;     // N*64
  float* x1      = y + (size_t)N * 64;       // N*128
  float* h2p     = pzp;                      // reuse pzp (dead after gather1): N*32

  const int nb = (N + 255) / 256;
  const int nw4 = (N + 3) / 4;
  const int poolBlocks = ((N + 3) / 4 < 768) ? (N + 3) / 4 : 768;

  k_zero<<<nb, 256, 0, stream>>>(cnt, N);
  k_count<<<1024, 256, 0, stream>>>(dstp, cnt, E);
  k_scan1<<<P, 256, 0, stream>>>(cnt, rowp, partial, N);
  k_scan2<<<1, 256, 0, stream>>>(partial, P);
  k_scan3<<<P, 256, 0, stream>>>(rowp, partial, cursor, cnt, dinv, N);
  k_edge_fill<<<1024, 256, 0, stream>>>(src, dstp, cursor, esrc, E);
  k_wc<<<33, 256, 0, stream>>>(Wout, bout, W1, Wc, bc);
  k_pool<<<poolBlocks, 256, 0, stream>>>(X, mask, WE, bE, WA, bA, dinv, pzp, N);
  k_gather1<<<nw4, 256, 0, stream>>>(rowp, cnt, esrc, pzp, dinv, y, gbuf, N);
  k_gemm1<<<1024, 256, 0, stream>>>(y, gbuf, Wc, bc, x1, N);
  k_gemm2<<<1024, 256, 0, stream>>>(x1, b1, W2, dinv, h2p, N);
  k_gmlp<<<(B + 3) / 4, 256, 0, stream>>>(qidx, rowp, cnt, esrc, h2p, dinv, b2, Wm1, bm1, Wm2, bm2,
                                          (float*)d_out, B);
}